// Round 17
// baseline (262.113 us; speedup 1.0000x reference)
//
#include <hip/hip_runtime.h>

typedef unsigned short u16;
typedef __attribute__((ext_vector_type(8))) short short8;
typedef __attribute__((ext_vector_type(4))) float f32x4;

#define L_SEQ 2048
#define NHEAD 12
#define KVB 128
#define QBLK 128

__device__ __forceinline__ u16 f2bf(float f) {
    union { float f; unsigned u; } x; x.f = f;
    unsigned r = x.u + 0x7fffu + ((x.u >> 16) & 1u);
    return (u16)(r >> 16);
}
__device__ __forceinline__ float bf2f(u16 u) {
    union { unsigned u; float f; } x; x.u = ((unsigned)u) << 16;
    return x.f;
}
__device__ __forceinline__ float silu_f(float x) { return x / (1.f + __expf(-x)); }

// async global->LDS, 16B per lane. LDS dest must be wave-uniform base + lane*16.
__device__ __forceinline__ void gload16(const u16* g, u16* l) {
    __builtin_amdgcn_global_load_lds(
        (const __attribute__((address_space(1))) void*)g,
        (__attribute__((address_space(3))) void*)l, 16, 0, 0);
}

// ---------------- weight transposes + cond_mlp1 fused in one launch ----------------
// blocks [0,9216): W(K,N) -> Wt(N,K) tiles. blocks [9216,9312): cond_mlp1 K-split.
__global__ __launch_bounds__(256) void transpose_all(
    const float* __restrict__ S0, const float* __restrict__ S1,
    const float* __restrict__ S2, const float* __restrict__ S3,
    const float* __restrict__ S4, const float* __restrict__ S5,
    const float* __restrict__ S6,
    u16* __restrict__ D0, u16* __restrict__ D1, u16* __restrict__ D2,
    u16* __restrict__ D3, u16* __restrict__ D4, u16* __restrict__ D5,
    u16* __restrict__ D6,
    const float* __restrict__ c, const float* __restrict__ w1,
    float* __restrict__ part)
{
    int id = blockIdx.x;
    if (id >= 9216) {
        // cond_mlp1: 96 blocks -> (bx 0..11, by 0..7)
        int cid = id - 9216;
        int bx = cid % 12, by = cid / 12;
        int j = bx * 256 + threadIdx.x; // 0..3071
        int d0 = by * 96;
        float a0 = 0.f, a1 = 0.f;
        for (int d = d0; d < d0 + 96; ++d) {
            float w = w1[(size_t)d * 3072 + j];
            a0 += c[d] * w;
            a1 += c[768 + d] * w;
        }
        part[(size_t)(by * 2 + 0) * 3072 + j] = a0;
        part[(size_t)(by * 2 + 1) * 3072 + j] = a1;
        return;
    }
    const float* W; u16* Wt; int K, N, local;
    if (id < 2304) {
        int sec = id / 576; local = id - sec * 576; K = 768; N = 768;
        W  = (sec == 0) ? S0 : (sec == 1) ? S1 : (sec == 2) ? S2 : S3;
        Wt = (sec == 0) ? D0 : (sec == 1) ? D1 : (sec == 2) ? D2 : D3;
    } else if (id < 6912) {
        int sec = (id - 2304) / 2304; local = (id - 2304) - sec * 2304; K = 768; N = 3072;
        W = sec ? S5 : S4; Wt = sec ? D5 : D4;
    } else {
        local = id - 6912; K = 3072; N = 768; W = S6; Wt = D6;
    }
    int nx = N >> 5;
    int n0 = (local % nx) * 32, k0 = (local / nx) * 32;
    __shared__ float t[32][33];
    int tx = threadIdx.x & 31, ty = threadIdx.x >> 5; // ty 0..7
#pragma unroll
    for (int i = 0; i < 4; i++)
        t[ty + 8 * i][tx] = W[(size_t)(k0 + ty + 8 * i) * N + n0 + tx];
    __syncthreads();
#pragma unroll
    for (int i = 0; i < 4; i++)
        Wt[(size_t)(n0 + ty + 8 * i) * K + k0 + tx] = f2bf(t[tx][ty + 8 * i]);
}

// ---------------- cond MLP layer 2, K-split ----------
__global__ __launch_bounds__(256) void cond_mlp2(
    const float* __restrict__ part, const float* __restrict__ b1,
    const float* __restrict__ w2, float* __restrict__ c2part)
{
    __shared__ float hid[2][384];
    const int tid = threadIdx.x;
    const int d0 = blockIdx.y * 384;
    for (int i = tid; i < 768; i += 256) {
        int b = i / 384, dd = i - b * 384;
        float s = b1[d0 + dd];
#pragma unroll
        for (int p = 0; p < 8; p++) s += part[(size_t)(p * 2 + b) * 3072 + d0 + dd];
        hid[b][dd] = silu_f(s);
    }
    __syncthreads();
    int jj = tid & 63, kc = tid >> 6;
    int j = blockIdx.x * 64 + jj;
    float a0 = 0.f, a1 = 0.f;
    for (int dd = kc * 96; dd < kc * 96 + 96; ++dd) {
        float w = w2[(size_t)(d0 + dd) * 768 + j];
        a0 += hid[0][dd] * w;
        a1 += hid[1][dd] * w;
    }
    __shared__ float r0[256], r1[256];
    r0[tid] = a0; r1[tid] = a1;
    __syncthreads();
    if (kc == 0) {
        a0 = r0[jj] + r0[64 + jj] + r0[128 + jj] + r0[192 + jj];
        a1 = r1[jj] + r1[64 + jj] + r1[128 + jj] + r1[192 + jj];
        c2part[(size_t)(blockIdx.y * 2 + 0) * 768 + j] = a0;
        c2part[(size_t)(blockIdx.y * 2 + 1) * 768 + j] = a1;
    }
}

// ---------------- 5 modulation vectors ----------
__global__ __launch_bounds__(256) void mod_gemm(
    const float* __restrict__ c2part, const float* __restrict__ b2,
    const float* __restrict__ W0, const float* __restrict__ W1,
    const float* __restrict__ W2, const float* __restrict__ W3,
    const float* __restrict__ W4, float* __restrict__ out)
{
    __shared__ float c2s[2][768];
    const int tid = threadIdx.x;
    for (int i = tid; i < 1536; i += 256) {
        int b = i / 768, d = i - b * 768;
        float s = b2[d];
#pragma unroll
        for (int p = 0; p < 8; p++) s += c2part[(size_t)(p * 2 + b) * 768 + d];
        c2s[b][d] = s;
    }
    __syncthreads();
    int w = blockIdx.y;
    const float* W = (w == 0) ? W0 : (w == 1) ? W1 : (w == 2) ? W2 : (w == 3) ? W3 : W4;
    int jj = tid & 63, kc = tid >> 6; // 4 k-chunks of 192
    int j = blockIdx.x * 64 + jj;
    float a0 = 0.f, a1 = 0.f;
    for (int d = kc * 192; d < kc * 192 + 192; ++d) {
        float ww = W[(size_t)d * 768 + j];
        a0 += c2s[0][d] * ww;
        a1 += c2s[1][d] * ww;
    }
    __shared__ float r0[256], r1[256];
    r0[tid] = a0; r1[tid] = a1;
    __syncthreads();
    if (kc == 0) {
        a0 = r0[jj] + r0[64 + jj] + r0[128 + jj] + r0[192 + jj];
        a1 = r1[jj] + r1[64 + jj] + r1[128 + jj] + r1[192 + jj];
        out[(size_t)(w * 2 + 0) * 768 + j] = a0;
        out[(size_t)(w * 2 + 1) * 768 + j] = a1;
    }
}

// ---------------- fused RMSNorm * gamma_mod + beta_mod -> bf16 ----------
// IN==0: fp32 input; IN==1: bf16 input.
template<int IN>
__global__ __launch_bounds__(256) void rmsnorm_mod(
    const void* __restrict__ xin, const float* __restrict__ nw,
    const float* __restrict__ gamma, const float* __restrict__ beta,
    u16* __restrict__ hout)
{
    int row = blockIdx.x;      // 0..4095
    int b = row >> 11;         // L=2048
    int t = threadIdx.x;
    float v0, v1, v2;
    if (IN == 0) {
        const float* xr = (const float*)xin + (size_t)row * 768;
        v0 = xr[t]; v1 = xr[t + 256]; v2 = xr[t + 512];
    } else {
        const u16* xr = (const u16*)xin + (size_t)row * 768;
        v0 = bf2f(xr[t]); v1 = bf2f(xr[t + 256]); v2 = bf2f(xr[t + 512]);
    }
    float ss = v0 * v0 + v1 * v1 + v2 * v2;
#pragma unroll
    for (int m = 1; m < 64; m <<= 1) ss += __shfl_xor(ss, m);
    __shared__ float red[4];
    if ((t & 63) == 0) red[t >> 6] = ss;
    __syncthreads();
    float tot = red[0] + red[1] + red[2] + red[3];
    float rr = rsqrtf(tot * (1.f / 768.f) + 1e-6f);
    u16* ho = hout + (size_t)row * 768;
    const float* g = gamma + (size_t)b * 768;
    const float* be = beta + (size_t)b * 768;
#pragma unroll
    for (int i = 0; i < 3; i++) {
        int col = t + i * 256;
        float v = (i == 0) ? v0 : (i == 1) ? v1 : v2;
        ho[col] = f2bf(v * rr * nw[col] * g[col] + be[col]);
    }
}

// ===================== BK=64 swizzled-LDS GEMM family ==============================
// LDS tile rows are 64 u16 (128B); granule (16B) swizzle: LDS[r][g] holds source
// granule g^(r&7) (same involution staged and read -> bank-conflict-free).

// ---------------- QKV GEMM + fused RoPE + V-transpose epilogue ---------------------
__global__ __launch_bounds__(256) void gemm_qkv_rope(
    const u16* __restrict__ A, const u16* __restrict__ Bt,
    const float* __restrict__ fc, const float* __restrict__ fs,
    u16* __restrict__ qo, u16* __restrict__ ko, u16* __restrict__ vt,
    int M, int N, int K)
{
    const float QSCALE = 0.125f * 1.44269504f;
    __shared__ __align__(16) u16 As[2][128 * 64];
    __shared__ __align__(16) u16 Bs[2][128 * 64];
    const int tid = threadIdx.x;
    const int lane = tid & 63, wid = tid >> 6;
    const int lo = lane & 15, hi = lane >> 4;
    const int bm = blockIdx.x * 128, bn = blockIdx.y * 128;
    const int wrow = (wid >> 1) * 64, wcol = (wid & 1) * 64;

    f32x4 acc[4][4];
#pragma unroll
    for (int a = 0; a < 4; a++)
#pragma unroll
        for (int b = 0; b < 4; b++)
            acc[a][b] = (f32x4){0.f, 0.f, 0.f, 0.f};

    auto stage = [&](int buf, int k0) {
#pragma unroll
        for (int p = 0; p < 4; p++) {
            int ch = tid + p * 256;
            int r = ch >> 3, g = ch & 7;
            gload16(A + (size_t)(bm + r) * K + k0 + ((g ^ (r & 7)) * 8), &As[buf][ch * 8]);
        }
#pragma unroll
        for (int p = 0; p < 4; p++) {
            int ch = tid + p * 256;
            int r = ch >> 3, g = ch & 7;
            gload16(Bt + (size_t)(bn + r) * K + k0 + ((g ^ (r & 7)) * 8), &Bs[buf][ch * 8]);
        }
    };

    stage(0, 0);
    int cur = 0;
    const int NT = K >> 6;   // BK=64
    for (int t = 0; t < NT; t++) {
        __syncthreads();
        if (t + 1 < NT) stage(cur ^ 1, (t + 1) * 64);
        short8 af[4][2], bfr[4][2];
#pragma unroll
        for (int mi = 0; mi < 4; mi++) {
            int r = wrow + mi * 16 + lo;
#pragma unroll
            for (int h = 0; h < 2; h++)
                af[mi][h] = *(const short8*)(&As[cur][r * 64 + (((h * 4 + hi) ^ (r & 7)) * 8)]);
        }
#pragma unroll
        for (int nj = 0; nj < 4; nj++) {
            int r = wcol + nj * 16 + lo;
#pragma unroll
            for (int h = 0; h < 2; h++)
                bfr[nj][h] = *(const short8*)(&Bs[cur][r * 64 + (((h * 4 + hi) ^ (r & 7)) * 8)]);
        }
        __builtin_amdgcn_s_setprio(1);
#pragma unroll
        for (int mi = 0; mi < 4; mi++)
#pragma unroll
            for (int nj = 0; nj < 4; nj++) {
                acc[mi][nj] = __builtin_amdgcn_mfma_f32_16x16x32_bf16(af[mi][0], bfr[nj][0], acc[mi][nj], 0, 0, 0);
                acc[mi][nj] = __builtin_amdgcn_mfma_f32_16x16x32_bf16(af[mi][1], bfr[nj][1], acc[mi][nj], 0, 0, 0);
            }
        __builtin_amdgcn_s_setprio(0);
        cur ^= 1;
    }
    // epilogue: which = 0 Q / 1 K / 2 V (wave-uniform per block since 768 = 6*128)
    const int which = bn / 768;
    if (which == 2) {
#pragma unroll
        for (int mi = 0; mi < 4; mi++)
#pragma unroll
            for (int nj = 0; nj < 4; nj++) {
                int row0 = bm + wrow + mi * 16 + hi * 4;   // l base (mult of 4)
                int col = bn + wcol + nj * 16 + lo;
                int within = col - 1536;
                int h = within >> 6, d = within & 63;
                int l0 = row0 & (L_SEQ - 1), b = row0 >> 11;
                unsigned w0, w1;
                asm("v_cvt_pk_bf16_f32 %0, %1, %2" : "=v"(w0) : "v"(acc[mi][nj][0]), "v"(acc[mi][nj][1]));
                asm("v_cvt_pk_bf16_f32 %0, %1, %2" : "=v"(w1) : "v"(acc[mi][nj][2]), "v"(acc[mi][nj][3]));
                uint2 pk2; pk2.x = w0; pk2.y = w1;
                *(uint2*)(vt + (((size_t)(b * NHEAD + h)) * 64 + d) * L_SEQ + l0) = pk2;
            }
    } else {
#pragma unroll
        for (int mi = 0; mi < 4; mi++)
#pragma unroll
            for (int nj = 0; nj < 4; nj++)
#pragma unroll
                for (int i = 0; i < 4; i++) {
                    int row = bm + wrow + mi * 16 + hi * 4 + i;
                    int col = bn + wcol + nj * 16 + lo;
                    float v = acc[mi][nj][i];
                    int within = col - which * 768;
                    int h = within >> 6, d = within & 63;
                    int l = row & (L_SEQ - 1), b = row >> 11;
                    int dp = d >> 1;
                    float cc = fc[l * 32 + dp], sn = fs[l * 32 + dp];
                    float pv = __shfl_xor(v, 1);
                    float r_;
                    if ((lo & 1) == 0) r_ = v * cc - pv * sn;   // even d
                    else               r_ = pv * sn + v * cc;   // odd d
                    if (which == 0) r_ *= QSCALE;
                    u16* dst = (which == 0) ? qo : ko;
                    dst[(((size_t)(b * NHEAD + h)) * L_SEQ + l) * 64 + d] = f2bf(r_);
                }
    }
}

// ---------------- generic BK=64 GEMM, residual epilogue ----------------------------
// MODE 0: X fp32, out bf16  (O-proj -> ybuf bf16)
// MODE 1: X bf16, out fp32  (final -> d_out fp32)
template<int MODE>
__global__ __launch_bounds__(256) void gemm_res64(
    const u16* __restrict__ A, const u16* __restrict__ Bt,
    void* __restrict__ outp, const void* __restrict__ X, const float* __restrict__ coef,
    int M, int N, int K)
{
    __shared__ __align__(16) u16 As[2][64 * 64];
    __shared__ __align__(16) u16 Bs[2][128 * 64];
    const int tid = threadIdx.x;
    const int lane = tid & 63, wid = tid >> 6;
    const int lo = lane & 15, hi = lane >> 4;
    const int bm = blockIdx.x * 64, bn = blockIdx.y * 128;
    const int wrow = (wid >> 1) * 32, wcol = (wid & 1) * 64;

    f32x4 acc[2][4];
#pragma unroll
    for (int a = 0; a < 2; a++)
#pragma unroll
        for (int b = 0; b < 4; b++)
            acc[a][b] = (f32x4){0.f, 0.f, 0.f, 0.f};

    auto stage = [&](int buf, int k0) {
#pragma unroll
        for (int p = 0; p < 2; p++) {
            int ch = tid + p * 256;
            int r = ch >> 3, g = ch & 7;
            gload16(A + (size_t)(bm + r) * K + k0 + ((g ^ (r & 7)) * 8), &As[buf][ch * 8]);
        }
#pragma unroll
        for (int p = 0; p < 4; p++) {
            int ch = tid + p * 256;
            int r = ch >> 3, g = ch & 7;
            gload16(Bt + (size_t)(bn + r) * K + k0 + ((g ^ (r & 7)) * 8), &Bs[buf][ch * 8]);
        }
    };

    stage(0, 0);
    int cur = 0;
    const int NT = K >> 6;
    for (int t = 0; t < NT; t++) {
        __syncthreads();
        if (t + 1 < NT) stage(cur ^ 1, (t + 1) * 64);
        short8 af[2][2], bfr[4][2];
#pragma unroll
        for (int mi = 0; mi < 2; mi++) {
            int r = wrow + mi * 16 + lo;
#pragma unroll
            for (int h = 0; h < 2; h++)
                af[mi][h] = *(const short8*)(&As[cur][r * 64 + (((h * 4 + hi) ^ (r & 7)) * 8)]);
        }
#pragma unroll
        for (int nj = 0; nj < 4; nj++) {
            int r = wcol + nj * 16 + lo;
#pragma unroll
            for (int h = 0; h < 2; h++)
                bfr[nj][h] = *(const short8*)(&Bs[cur][r * 64 + (((h * 4 + hi) ^ (r & 7)) * 8)]);
        }
        __builtin_amdgcn_s_setprio(1);
#pragma unroll
        for (int mi = 0; mi < 2; mi++)
#pragma unroll
            for (int nj = 0; nj < 4; nj++) {
                acc[mi][nj] = __builtin_amdgcn_mfma_f32_16x16x32_bf16(af[mi][0], bfr[nj][0], acc[mi][nj], 0, 0, 0);
                acc[mi][nj] = __builtin_amdgcn_mfma_f32_16x16x32_bf16(af[mi][1], bfr[nj][1], acc[mi][nj], 0, 0, 0);
            }
        __builtin_amdgcn_s_setprio(0);
        cur ^= 1;
    }
#pragma unroll
    for (int mi = 0; mi < 2; mi++)
#pragma unroll
        for (int nj = 0; nj < 4; nj++)
#pragma unroll
            for (int i = 0; i < 4; i++) {
                int row = bm + wrow + mi * 16 + hi * 4 + i;
                int col = bn + wcol + nj * 16 + lo;
                size_t idx = (size_t)row * N + col;
                int b = row >> 11;
                float base = (MODE == 0) ? ((const float*)X)[idx]
                                         : bf2f(((const u16*)X)[idx]);
                float v = base + acc[mi][nj][i] * coef[(size_t)b * N + col];
                if (MODE == 0) ((u16*)outp)[idx] = f2bf(v);
                else           ((float*)outp)[idx] = v;
            }
}

// ---------------- fused FFN1, BK=64: ff = bf16(silu(A@G^T) * (A@H^T)) --------------
__global__ __launch_bounds__(256) void gemm_ffn1(
    const u16* __restrict__ A, const u16* __restrict__ Gt, const u16* __restrict__ Ht,
    u16* __restrict__ ff, int M, int N, int K)
{
    __shared__ __align__(16) u16 As[2][128 * 64];
    __shared__ __align__(16) u16 Gs[2][64 * 64];
    __shared__ __align__(16) u16 Hs[2][64 * 64];
    const int tid = threadIdx.x;
    const int lane = tid & 63, wid = tid >> 6;
    const int lo = lane & 15, hi = lane >> 4;
    const int bm = blockIdx.x * 128, bn = blockIdx.y * 64;
    const int wrow = (wid >> 1) * 64, wcol = (wid & 1) * 32;

    f32x4 ag[4][2], ah[4][2];
#pragma unroll
    for (int a = 0; a < 4; a++)
#pragma unroll
        for (int b = 0; b < 2; b++) {
            ag[a][b] = (f32x4){0.f, 0.f, 0.f, 0.f};
            ah[a][b] = (f32x4){0.f, 0.f, 0.f, 0.f};
        }

    auto stage = [&](int buf, int k0) {
#pragma unroll
        for (int p = 0; p < 4; p++) {
            int ch = tid + p * 256;
            int r = ch >> 3, g = ch & 7;
            gload16(A + (size_t)(bm + r) * K + k0 + ((g ^ (r & 7)) * 8), &As[buf][ch * 8]);
        }
#pragma unroll
        for (int p = 0; p < 2; p++) {
            int ch = tid + p * 256;
            int r = ch >> 3, g = ch & 7;
            gload16(Gt + (size_t)(bn + r) * K + k0 + ((g ^ (r & 7)) * 8), &Gs[buf][ch * 8]);
        }
#pragma unroll
        for (int p = 0; p < 2; p++) {
            int ch = tid + p * 256;
            int r = ch >> 3, g = ch & 7;
            gload16(Ht + (size_t)(bn + r) * K + k0 + ((g ^ (r & 7)) * 8), &Hs[buf][ch * 8]);
        }
    };

    stage(0, 0);
    int cur = 0;
    const int NT = K >> 6;
    for (int t = 0; t < NT; t++) {
        __syncthreads();
        if (t + 1 < NT) stage(cur ^ 1, (t + 1) * 64);
        short8 af[4][2], gf[2][2], hf[2][2];
#pragma unroll
        for (int mi = 0; mi < 4; mi++) {
            int r = wrow + mi * 16 + lo;
#pragma unroll
            for (int h = 0; h < 2; h++)
                af[mi][h] = *(const short8*)(&As[cur][r * 64 + (((h * 4 + hi) ^ (r & 7)) * 8)]);
        }
#pragma unroll
        for (int nj = 0; nj < 2; nj++) {
            int r = wcol + nj * 16 + lo;
#pragma unroll
            for (int h = 0; h < 2; h++) {
                gf[nj][h] = *(const short8*)(&Gs[cur][r * 64 + (((h * 4 + hi) ^ (r & 7)) * 8)]);
                hf[nj][h] = *(const short8*)(&Hs[cur][r * 64 + (((h * 4 + hi) ^ (r & 7)) * 8)]);
            }
        }
        __builtin_amdgcn_s_setprio(1);
#pragma unroll
        for (int mi = 0; mi < 4; mi++)
#pragma unroll
            for (int nj = 0; nj < 2; nj++) {
                ag[mi][nj] = __builtin_amdgcn_mfma_f32_16x16x32_bf16(af[mi][0], gf[nj][0], ag[mi][nj], 0, 0, 0);
                ag[mi][nj] = __builtin_amdgcn_mfma_f32_16x16x32_bf16(af[mi][1], gf[nj][1], ag[mi][nj], 0, 0, 0);
                ah[mi][nj] = __builtin_amdgcn_mfma_f32_16x16x32_bf16(af[mi][0], hf[nj][0], ah[mi][nj], 0, 0, 0);
                ah[mi][nj] = __builtin_amdgcn_mfma_f32_16x16x32_bf16(af[mi][1], hf[nj][1], ah[mi][nj], 0, 0, 0);
            }
        __builtin_amdgcn_s_setprio(0);
        cur ^= 1;
    }
#pragma unroll
    for (int mi = 0; mi < 4; mi++)
#pragma unroll
        for (int nj = 0; nj < 2; nj++)
#pragma unroll
            for (int i = 0; i < 4; i++) {
                int row = bm + wrow + mi * 16 + hi * 4 + i;
                int col = bn + wcol + nj * 16 + lo;
                ff[(size_t)row * N + col] = f2bf(silu_f(ag[mi][nj][i]) * ah[mi][nj][i]);
            }
}

// ---------------- flash attention: 512 threads (8 waves), QBLK=128, KVB=128 --------
// kk-interleaved softmax/PV: per kk {8 exp2 -> 2 packs -> 2 ds_writes -> pa read ->
// 4 PV MFMA}, so kk+1's exp2 overlaps kk's MFMAs and each pa read waits only on its
// own 2 writes (per-wave in-order DS). Math/addresses identical to prior version.
__global__ __launch_bounds__(512) void attn_fwd(
    const u16* __restrict__ q, const u16* __restrict__ k, const u16* __restrict__ vt,
    u16* __restrict__ outp)
{
    __shared__ __align__(16) u16 Kb[KVB * 64];      // 16 KB
    __shared__ __align__(16) u16 Vb[64 * KVB];      // 16 KB
    __shared__ __align__(16) u16 Ps[8][16 * KVB];   // 32 KB
    const int tid = threadIdx.x;
    const int lane = tid & 63, wid = tid >> 6;      // 8 waves
    const int lo = lane & 15, hi = lane >> 4;
    const int lid = blockIdx.x;
    const int xcd = lid & 7, li = lid >> 3;          // li 0..47
    const int bh = xcd * 3 + (li >> 4);              // 3 heads per XCD
    const int qt = li & 15;                          // 16 q-tiles of 128
    const int b = bh / NHEAD, h = bh % NHEAD;
    const int q0 = qt * QBLK + wid * 16;
    const u16* qb = q + ((size_t)bh * L_SEQ + q0) * 64;
    const u16* kbase = k + (size_t)bh * L_SEQ * 64;
    const u16* vbase = vt + (size_t)bh * 64 * L_SEQ;

    short8 qa0 = *(const short8*)(qb + lo * 64 + hi * 8);
    short8 qa1 = *(const short8*)(qb + lo * 64 + 32 + hi * 8);

    f32x4 oacc[4];
#pragma unroll
    for (int dt = 0; dt < 4; dt++) oacc[dt] = (f32x4){0.f, 0.f, 0.f, 0.f};
    float m_ = -1e30f, ls = 0.f;

    const int rk = tid >> 3, gk = tid & 7;
    const u16* ka = kbase + (size_t)rk * 64 + ((gk ^ (rk & 7)) * 8);
    const int rv = tid >> 4, gv = tid & 15;
    const u16* va = vbase + (size_t)rv * L_SEQ + ((gv ^ (rv & 15)) * 8);
    u16* kdst = &Kb[tid * 8];
    u16* vdst = &Vb[tid * 8];

    int4 kr0, kr1, vr0, vr1;
    kr0 = *(const int4*)(ka);
    kr1 = *(const int4*)(ka + 4096);
    vr0 = *(const int4*)(va);
    vr1 = *(const int4*)(va + 65536);

    const int NT = L_SEQ / KVB;   // 16
    u16* pw = &Ps[wid][0];
    const int pkey = lo << 3;
    for (int t = 0; t < NT; t++) {
        __syncthreads();
        *(int4*)(kdst)        = kr0;
        *(int4*)(kdst + 4096) = kr1;
        *(int4*)(vdst)        = vr0;
        *(int4*)(vdst + 4096) = vr1;
        __syncthreads();
        if (t + 1 < NT) {
            int kv0 = (t + 1) * KVB;
            const u16* kan = ka + (size_t)kv0 * 64;
            const u16* van = va + kv0;
            kr0 = *(const int4*)(kan);
            kr1 = *(const int4*)(kan + 4096);
            vr0 = *(const int4*)(van);
            vr1 = *(const int4*)(van + 65536);
        }
        // QK^T (swapped): s[nt] lane holds S[q=lo][k=nt*16+hi*4+r]
        f32x4 s[8];
#pragma unroll
        for (int nt = 0; nt < 8; nt++) {
            int kr_ = nt * 16 + lo;
            const u16* kp = &Kb[kr_ * 64];
            int key = (kr_ & 7) << 3;
            short8 kf0 = *(const short8*)(kp + ((hi * 8) ^ key));
            short8 kf1 = *(const short8*)(kp + ((32 + hi * 8) ^ key));
            __builtin_amdgcn_s_setprio(1);
            f32x4 z = (f32x4){0.f, 0.f, 0.f, 0.f};
            z = __builtin_amdgcn_mfma_f32_16x16x32_bf16(kf0, qa0, z, 0, 0, 0);
            s[nt] = __builtin_amdgcn_mfma_f32_16x16x32_bf16(kf1, qa1, s[nt] = z, 0, 0, 0);
            __builtin_amdgcn_s_setprio(0);
        }
        // row max tree + 2 cross-hi shfls
        float t0 = fmaxf(fmaxf(s[0][0], s[0][1]), fmaxf(s[0][2], s[0][3]));
        float t1 = fmaxf(fmaxf(s[1][0], s[1][1]), fmaxf(s[1][2], s[1][3]));
        float t2 = fmaxf(fmaxf(s[2][0], s[2][1]), fmaxf(s[2][2], s[2][3]));
        float t3 = fmaxf(fmaxf(s[3][0], s[3][1]), fmaxf(s[3][2], s[3][3]));
        float t4 = fmaxf(fmaxf(s[4][0], s[4][1]), fmaxf(s[4][2], s[4][3]));
        float t5 = fmaxf(fmaxf(s[5][0], s[5][1]), fmaxf(s[5][2], s[5][3]));
        float t6 = fmaxf(fmaxf(s[6][0], s[6][1]), fmaxf(s[6][2], s[6][3]));
        float t7 = fmaxf(fmaxf(s[7][0], s[7][1]), fmaxf(s[7][2], s[7][3]));
        float pmax = fmaxf(fmaxf(fmaxf(t0, t1), fmaxf(t2, t3)),
                           fmaxf(fmaxf(t4, t5), fmaxf(t6, t7)));
        pmax = fmaxf(pmax, __shfl_xor(pmax, 16));
        pmax = fmaxf(pmax, __shfl_xor(pmax, 32));
        // defer-max (T13)
        if (!__all(pmax - m_ <= 8.f)) {
            float mn = fmaxf(m_, pmax);
            float al = exp2f(m_ - mn);
            m_ = mn;
            ls *= al;
#pragma unroll
            for (int dt = 0; dt < 4; dt++) oacc[dt] *= al;
        }
        // kk-interleaved: exp -> pack -> write -> pa read -> PV, per 32-k chunk
        float rsA = 0.f, rsB = 0.f, rsC = 0.f, rsD = 0.f;
#pragma unroll
        for (int kk = 0; kk < 4; kk++) {
            const int nt0 = 2 * kk, nt1 = 2 * kk + 1;
            float p00 = exp2f(s[nt0][0] - m_);
            float p01 = exp2f(s[nt0][1] - m_);
            float p02 = exp2f(s[nt0][2] - m_);
            float p03 = exp2f(s[nt0][3] - m_);
            float p10 = exp2f(s[nt1][0] - m_);
            float p11 = exp2f(s[nt1][1] - m_);
            float p12 = exp2f(s[nt1][2] - m_);
            float p13 = exp2f(s[nt1][3] - m_);
            rsA += p00 + p10; rsB += p01 + p11;
            rsC += p02 + p12; rsD += p03 + p13;
            unsigned w0, w1, w2, w3;
            asm("v_cvt_pk_bf16_f32 %0, %1, %2" : "=v"(w0) : "v"(p00), "v"(p01));
            asm("v_cvt_pk_bf16_f32 %0, %1, %2" : "=v"(w1) : "v"(p02), "v"(p03));
            asm("v_cvt_pk_bf16_f32 %0, %1, %2" : "=v"(w2) : "v"(p10), "v"(p11));
            asm("v_cvt_pk_bf16_f32 %0, %1, %2" : "=v"(w3) : "v"(p12), "v"(p13));
            uint2 pkA; pkA.x = w0; pkA.y = w1;
            uint2 pkB; pkB.x = w2; pkB.y = w3;
            *(uint2*)(pw + lo * KVB + ((nt0 * 16 + hi * 4) ^ pkey)) = pkA;
            *(uint2*)(pw + lo * KVB + ((nt1 * 16 + hi * 4) ^ pkey)) = pkB;
            short8 pa = *(const short8*)(pw + lo * KVB + ((kk * 32 + hi * 8) ^ pkey));
            __builtin_amdgcn_s_setprio(1);
#pragma unroll
            for (int dt = 0; dt < 4; dt++) {
                int vr_ = dt * 16 + lo;
                const u16* vp = &Vb[vr_ * KVB];
                int vkey = (vr_ & 15) << 3;
                short8 vf = *(const short8*)(vp + ((kk * 32 + hi * 8) ^ vkey));
                oacc[dt] = __builtin_amdgcn_mfma_f32_16x16x32_bf16(vf, pa, oacc[dt], 0, 0, 0);
            }
            __builtin_amdgcn_s_setprio(0);
        }
        ls += (rsA + rsB) + (rsC + rsD);
    }
    // epilogue: deferred cross-lane ls reduce, then pack 4 -> one 8B store
    ls += __shfl_xor(ls, 16);
    ls += __shfl_xor(ls, 32);
    float inv = 1.f / ls;
    int qrow = q0 + lo;
    u16* orow = outp + ((size_t)(b * L_SEQ + qrow)) * 768 + h * 64;
#pragma unroll
    for (int dt = 0; dt < 4; dt++) {
        unsigned w0, w1;
        float o0 = oacc[dt][0] * inv, o1 = oacc[dt][1] * inv;
        float o2 = oacc[dt][2] * inv, o3 = oacc[dt][3] * inv;
        asm("v_cvt_pk_bf16_f32 %0, %1, %2" : "=v"(w0) : "v"(o0), "v"(o1));
        asm("v_cvt_pk_bf16_f32 %0, %1, %2" : "=v"(w1) : "v"(o2), "v"(o3));
        uint2 pk2; pk2.x = w0; pk2.y = w1;
        *(uint2*)(orow + dt * 16 + hi * 4) = pk2;
    }
}

extern "C" void kernel_launch(void* const* d_in, const int* in_sizes, int n_in,
                              void* d_out, int out_size, void* d_ws, size_t ws_size,
                              hipStream_t stream)
{
    const float* x      = (const float*)d_in[0];
    const float* c      = (const float*)d_in[1];
    const float* fcos   = (const float*)d_in[2];
    const float* fsin   = (const float*)d_in[3];
    const float* Wq     = (const float*)d_in[4];
    const float* Wk     = (const float*)d_in[5];
    const float* Wv     = (const float*)d_in[6];
    const float* Wo     = (const float*)d_in[7];
    const float* cw1    = (const float*)d_in[8];
    const float* cb1    = (const float*)d_in[9];
    const float* cw2    = (const float*)d_in[10];
    const float* cb2    = (const float*)d_in[11];
    const float* anw    = (const float*)d_in[12];
    const float* Walpha = (const float*)d_in[13];
    const float* Wbeta  = (const float*)d_in[14];
    const float* Wgamma = (const float*)d_in[15];
    const float* Wgate  = (const float*)d_in[16];
    const float* Whid   = (const float*)d_in[17];
    const float* Wout   = (const float*)d_in[18];
    const float* fnw    = (const float*)d_in[19];
    const float* Wbetaf = (const float*)d_in[20];
    const float* Wgammaf= (const float*)d_in[21];

    const int M = 4096; // B*L
    char* ws = (char*)d_ws;
    size_t off = 0;
    auto alloc = [&](size_t bytes) -> char* {
        char* p = ws + off;
        off += (bytes + 255) & ~(size_t)255;
        return p;
    };
    u16* wq_t   = (u16*)alloc((size_t)768 * 768 * 2);
    u16* wk_t   = (u16*)alloc((size_t)768 * 768 * 2);
    u16* wv_t   = (u16*)alloc((size_t)768 * 768 * 2);
    u16* wo_t   = (u16*)alloc((size_t)768 * 768 * 2);
    u16* gate_t = (u16*)alloc((size_t)3072 * 768 * 2);
    u16* hid_t  = (u16*)alloc((size_t)3072 * 768 * 2);
    u16* out_t  = (u16*)alloc((size_t)768 * 3072 * 2);
    float* part1 = (float*)alloc((size_t)8 * 2 * 3072 * 4);
    float* part2 = (float*)alloc((size_t)8 * 2 * 768 * 4);
    float* mods = (float*)alloc(5 * 2 * 768 * 4);
    u16* hbuf   = (u16*)alloc((size_t)M * 768 * 2);
    u16* qrope  = (u16*)alloc((size_t)M * 768 * 2);
    u16* krope  = (u16*)alloc((size_t)M * 768 * 2);
    u16* vtb    = (u16*)alloc((size_t)M * 768 * 2);
    u16* attnh  = (u16*)alloc((size_t)M * 768 * 2);
    u16* ybuf   = (u16*)alloc((size_t)M * 768 * 2);
    u16* ffbuf  = (u16*)alloc((size_t)M * 3072 * 2);

    // 1. ALL weight transposes + cond_mlp1 in one launch
    transpose_all<<<9312, 256, 0, stream>>>(
        Wq, Wk, Wv, Wo, Wgate, Whid, Wout,
        wq_t, wk_t, wv_t, wo_t, gate_t, hid_t, out_t,
        c, cw1, part1);

    // 2. conditioning path (remaining)
    cond_mlp2<<<dim3(12, 8), 256, 0, stream>>>(part1, cb1, cw2, part2);
    mod_gemm<<<dim3(12, 5), 256, 0, stream>>>(
        part2, cb2, Wgamma, Wbeta, Walpha, Wgammaf, Wbetaf, mods);

    // 3. h = rms(x)*gamma_a + beta_a (fp32 input)
    rmsnorm_mod<0><<<M, 256, 0, stream>>>(x, anw, mods + 0 * 1536, mods + 1 * 1536, hbuf);

    // 4. fused QKV GEMM + RoPE + V-transpose epilogue
    gemm_qkv_rope<<<dim3(32, 18), 256, 0, stream>>>(
        hbuf, wq_t, fcos, fsin, qrope, krope, vtb, M, 2304, 768);

    // 5. attention -> attnh (B,L,D) bf16
    attn_fwd<<<dim3(384), 512, 0, stream>>>(qrope, krope, vtb, attnh);

    // 6. O-proj + residual: ybuf(bf16) = x + (attnh @ Wo) * alpha_a
    gemm_res64<0><<<dim3(64, 6), 256, 0, stream>>>(
        attnh, wo_t, ybuf, x, mods + 2 * 1536, M, 768, 768);

    // 7. h2 = rms(y)*gamma_f + beta_f (bf16 input)
    rmsnorm_mod<1><<<M, 256, 0, stream>>>(ybuf, fnw, mods + 3 * 1536, mods + 4 * 1536, hbuf);

    // 8. fused gate/hidden GEMM + silu-mul -> ffbuf
    gemm_ffn1<<<dim3(32, 48), 256, 0, stream>>>(
        hbuf, gate_t, hid_t, ffbuf, M, 3072, 768);

    // 9. out(fp32) = y(bf16) + (ff @ Wout) * gamma_f
    gemm_res64<1><<<dim3(64, 6), 256, 0, stream>>>(
        ffbuf, out_t, d_out, ybuf, mods + 3 * 1536, M, 768, 3072);
}

// Round 18
// 245.484 us; speedup vs baseline: 1.0677x; 1.0677x over previous
//
#include <hip/hip_runtime.h>

typedef unsigned short u16;
typedef __attribute__((ext_vector_type(8))) short short8;
typedef __attribute__((ext_vector_type(4))) float f32x4;

#define L_SEQ 2048
#define NHEAD 12
#define KVB 128
#define QBLK 128

__device__ __forceinline__ u16 f2bf(float f) {
    union { float f; unsigned u; } x; x.f = f;
    unsigned r = x.u + 0x7fffu + ((x.u >> 16) & 1u);
    return (u16)(r >> 16);
}
__device__ __forceinline__ float bf2f(u16 u) {
    union { unsigned u; float f; } x; x.u = ((unsigned)u) << 16;
    return x.f;
}
__device__ __forceinline__ float silu_f(float x) { return x / (1.f + __expf(-x)); }

// async global->LDS, 16B per lane. LDS dest must be wave-uniform base + lane*16.
__device__ __forceinline__ void gload16(const u16* g, u16* l) {
    __builtin_amdgcn_global_load_lds(
        (const __attribute__((address_space(1))) void*)g,
        (__attribute__((address_space(3))) void*)l, 16, 0, 0);
}

// ---------------- ALL weight transposes in one launch: W(K,N) -> Wt(N,K) -----------
__global__ __launch_bounds__(256) void transpose_all(
    const float* __restrict__ S0, const float* __restrict__ S1,
    const float* __restrict__ S2, const float* __restrict__ S3,
    const float* __restrict__ S4, const float* __restrict__ S5,
    const float* __restrict__ S6,
    u16* __restrict__ D0, u16* __restrict__ D1, u16* __restrict__ D2,
    u16* __restrict__ D3, u16* __restrict__ D4, u16* __restrict__ D5,
    u16* __restrict__ D6)
{
    int id = blockIdx.x;
    const float* W; u16* Wt; int K, N, local;
    if (id < 2304) {
        int sec = id / 576; local = id - sec * 576; K = 768; N = 768;
        W  = (sec == 0) ? S0 : (sec == 1) ? S1 : (sec == 2) ? S2 : S3;
        Wt = (sec == 0) ? D0 : (sec == 1) ? D1 : (sec == 2) ? D2 : D3;
    } else if (id < 6912) {
        int sec = (id - 2304) / 2304; local = (id - 2304) - sec * 2304; K = 768; N = 3072;
        W = sec ? S5 : S4; Wt = sec ? D5 : D4;
    } else {
        local = id - 6912; K = 3072; N = 768; W = S6; Wt = D6;
    }
    int nx = N >> 5;
    int n0 = (local % nx) * 32, k0 = (local / nx) * 32;
    __shared__ float t[32][33];
    int tx = threadIdx.x & 31, ty = threadIdx.x >> 5; // ty 0..7
#pragma unroll
    for (int i = 0; i < 4; i++)
        t[ty + 8 * i][tx] = W[(size_t)(k0 + ty + 8 * i) * N + n0 + tx];
    __syncthreads();
#pragma unroll
    for (int i = 0; i < 4; i++)
        Wt[(size_t)(n0 + ty + 8 * i) * K + k0 + tx] = f2bf(t[tx][ty + 8 * i]);
}

// ---------------- cond MLP layer 1, K-split ----------
__global__ __launch_bounds__(256) void cond_mlp1(
    const float* __restrict__ c, const float* __restrict__ w1, float* __restrict__ part)
{
    int j = blockIdx.x * 256 + threadIdx.x; // 0..3071
    int d0 = blockIdx.y * 96;
    float a0 = 0.f, a1 = 0.f;
    for (int d = d0; d < d0 + 96; ++d) {
        float w = w1[(size_t)d * 3072 + j];
        a0 += c[d] * w;
        a1 += c[768 + d] * w;
    }
    part[(size_t)(blockIdx.y * 2 + 0) * 3072 + j] = a0;
    part[(size_t)(blockIdx.y * 2 + 1) * 3072 + j] = a1;
}

// ---------------- cond MLP layer 2, K-split ----------
__global__ __launch_bounds__(256) void cond_mlp2(
    const float* __restrict__ part, const float* __restrict__ b1,
    const float* __restrict__ w2, float* __restrict__ c2part)
{
    __shared__ float hid[2][384];
    const int tid = threadIdx.x;
    const int d0 = blockIdx.y * 384;
    for (int i = tid; i < 768; i += 256) {
        int b = i / 384, dd = i - b * 384;
        float s = b1[d0 + dd];
#pragma unroll
        for (int p = 0; p < 8; p++) s += part[(size_t)(p * 2 + b) * 3072 + d0 + dd];
        hid[b][dd] = silu_f(s);
    }
    __syncthreads();
    int jj = tid & 63, kc = tid >> 6;
    int j = blockIdx.x * 64 + jj;
    float a0 = 0.f, a1 = 0.f;
    for (int dd = kc * 96; dd < kc * 96 + 96; ++dd) {
        float w = w2[(size_t)(d0 + dd) * 768 + j];
        a0 += hid[0][dd] * w;
        a1 += hid[1][dd] * w;
    }
    __shared__ float r0[256], r1[256];
    r0[tid] = a0; r1[tid] = a1;
    __syncthreads();
    if (kc == 0) {
        a0 = r0[jj] + r0[64 + jj] + r0[128 + jj] + r0[192 + jj];
        a1 = r1[jj] + r1[64 + jj] + r1[128 + jj] + r1[192 + jj];
        c2part[(size_t)(blockIdx.y * 2 + 0) * 768 + j] = a0;
        c2part[(size_t)(blockIdx.y * 2 + 1) * 768 + j] = a1;
    }
}

// ---------------- 5 modulation vectors ----------
__global__ __launch_bounds__(256) void mod_gemm(
    const float* __restrict__ c2part, const float* __restrict__ b2,
    const float* __restrict__ W0, const float* __restrict__ W1,
    const float* __restrict__ W2, const float* __restrict__ W3,
    const float* __restrict__ W4, float* __restrict__ out)
{
    __shared__ float c2s[2][768];
    const int tid = threadIdx.x;
    for (int i = tid; i < 1536; i += 256) {
        int b = i / 768, d = i - b * 768;
        float s = b2[d];
#pragma unroll
        for (int p = 0; p < 8; p++) s += c2part[(size_t)(p * 2 + b) * 768 + d];
        c2s[b][d] = s;
    }
    __syncthreads();
    int w = blockIdx.y;
    const float* W = (w == 0) ? W0 : (w == 1) ? W1 : (w == 2) ? W2 : (w == 3) ? W3 : W4;
    int jj = tid & 63, kc = tid >> 6; // 4 k-chunks of 192
    int j = blockIdx.x * 64 + jj;
    float a0 = 0.f, a1 = 0.f;
    for (int d = kc * 192; d < kc * 192 + 192; ++d) {
        float ww = W[(size_t)d * 768 + j];
        a0 += c2s[0][d] * ww;
        a1 += c2s[1][d] * ww;
    }
    __shared__ float r0[256], r1[256];
    r0[tid] = a0; r1[tid] = a1;
    __syncthreads();
    if (kc == 0) {
        a0 = r0[jj] + r0[64 + jj] + r0[128 + jj] + r0[192 + jj];
        a1 = r1[jj] + r1[64 + jj] + r1[128 + jj] + r1[192 + jj];
        out[(size_t)(w * 2 + 0) * 768 + j] = a0;
        out[(size_t)(w * 2 + 1) * 768 + j] = a1;
    }
}

// ---------------- fused RMSNorm * gamma_mod + beta_mod -> bf16 ----------
// IN==0: fp32 input; IN==1: bf16 input.
template<int IN>
__global__ __launch_bounds__(256) void rmsnorm_mod(
    const void* __restrict__ xin, const float* __restrict__ nw,
    const float* __restrict__ gamma, const float* __restrict__ beta,
    u16* __restrict__ hout)
{
    int row = blockIdx.x;      // 0..4095
    int b = row >> 11;         // L=2048
    int t = threadIdx.x;
    float v0, v1, v2;
    if (IN == 0) {
        const float* xr = (const float*)xin + (size_t)row * 768;
        v0 = xr[t]; v1 = xr[t + 256]; v2 = xr[t + 512];
    } else {
        const u16* xr = (const u16*)xin + (size_t)row * 768;
        v0 = bf2f(xr[t]); v1 = bf2f(xr[t + 256]); v2 = bf2f(xr[t + 512]);
    }
    float ss = v0 * v0 + v1 * v1 + v2 * v2;
#pragma unroll
    for (int m = 1; m < 64; m <<= 1) ss += __shfl_xor(ss, m);
    __shared__ float red[4];
    if ((t & 63) == 0) red[t >> 6] = ss;
    __syncthreads();
    float tot = red[0] + red[1] + red[2] + red[3];
    float rr = rsqrtf(tot * (1.f / 768.f) + 1e-6f);
    u16* ho = hout + (size_t)row * 768;
    const float* g = gamma + (size_t)b * 768;
    const float* be = beta + (size_t)b * 768;
#pragma unroll
    for (int i = 0; i < 3; i++) {
        int col = t + i * 256;
        float v = (i == 0) ? v0 : (i == 1) ? v1 : v2;
        ho[col] = f2bf(v * rr * nw[col] * g[col] + be[col]);
    }
}

// ===================== BK=64 swizzled-LDS GEMM family ==============================
// LDS tile rows are 64 u16 (128B); granule (16B) swizzle: LDS[r][g] holds source
// granule g^(r&7) (same involution staged and read -> bank-conflict-free).

// ---------------- QKV GEMM + fused RoPE + V-transpose epilogue ---------------------
// Q cols [0,768): rope*QSCALE -> qo(B,H,L,64). K cols [768,1536): rope -> ko.
// V cols [1536,2304): directly transposed -> vt(B,H,64,L) via packed 8B stores.
__global__ __launch_bounds__(256) void gemm_qkv_rope(
    const u16* __restrict__ A, const u16* __restrict__ Bt,
    const float* __restrict__ fc, const float* __restrict__ fs,
    u16* __restrict__ qo, u16* __restrict__ ko, u16* __restrict__ vt,
    int M, int N, int K)
{
    const float QSCALE = 0.125f * 1.44269504f;
    __shared__ __align__(16) u16 As[2][128 * 64];
    __shared__ __align__(16) u16 Bs[2][128 * 64];
    const int tid = threadIdx.x;
    const int lane = tid & 63, wid = tid >> 6;
    const int lo = lane & 15, hi = lane >> 4;
    const int bm = blockIdx.x * 128, bn = blockIdx.y * 128;
    const int wrow = (wid >> 1) * 64, wcol = (wid & 1) * 64;

    f32x4 acc[4][4];
#pragma unroll
    for (int a = 0; a < 4; a++)
#pragma unroll
        for (int b = 0; b < 4; b++)
            acc[a][b] = (f32x4){0.f, 0.f, 0.f, 0.f};

    auto stage = [&](int buf, int k0) {
#pragma unroll
        for (int p = 0; p < 4; p++) {
            int ch = tid + p * 256;
            int r = ch >> 3, g = ch & 7;
            gload16(A + (size_t)(bm + r) * K + k0 + ((g ^ (r & 7)) * 8), &As[buf][ch * 8]);
        }
#pragma unroll
        for (int p = 0; p < 4; p++) {
            int ch = tid + p * 256;
            int r = ch >> 3, g = ch & 7;
            gload16(Bt + (size_t)(bn + r) * K + k0 + ((g ^ (r & 7)) * 8), &Bs[buf][ch * 8]);
        }
    };

    stage(0, 0);
    int cur = 0;
    const int NT = K >> 6;   // BK=64
    for (int t = 0; t < NT; t++) {
        __syncthreads();
        if (t + 1 < NT) stage(cur ^ 1, (t + 1) * 64);
        short8 af[4][2], bfr[4][2];
#pragma unroll
        for (int mi = 0; mi < 4; mi++) {
            int r = wrow + mi * 16 + lo;
#pragma unroll
            for (int h = 0; h < 2; h++)
                af[mi][h] = *(const short8*)(&As[cur][r * 64 + (((h * 4 + hi) ^ (r & 7)) * 8)]);
        }
#pragma unroll
        for (int nj = 0; nj < 4; nj++) {
            int r = wcol + nj * 16 + lo;
#pragma unroll
            for (int h = 0; h < 2; h++)
                bfr[nj][h] = *(const short8*)(&Bs[cur][r * 64 + (((h * 4 + hi) ^ (r & 7)) * 8)]);
        }
        __builtin_amdgcn_s_setprio(1);
#pragma unroll
        for (int mi = 0; mi < 4; mi++)
#pragma unroll
            for (int nj = 0; nj < 4; nj++) {
                acc[mi][nj] = __builtin_amdgcn_mfma_f32_16x16x32_bf16(af[mi][0], bfr[nj][0], acc[mi][nj], 0, 0, 0);
                acc[mi][nj] = __builtin_amdgcn_mfma_f32_16x16x32_bf16(af[mi][1], bfr[nj][1], acc[mi][nj], 0, 0, 0);
            }
        __builtin_amdgcn_s_setprio(0);
        cur ^= 1;
    }
    // epilogue: which = 0 Q / 1 K / 2 V (wave-uniform per block since 768 = 6*128)
    const int which = bn / 768;
    if (which == 2) {
        // V: write transposed. Lane holds 4 consecutive l (i=0..3) at fixed d.
#pragma unroll
        for (int mi = 0; mi < 4; mi++)
#pragma unroll
            for (int nj = 0; nj < 4; nj++) {
                int row0 = bm + wrow + mi * 16 + hi * 4;   // l base (mult of 4)
                int col = bn + wcol + nj * 16 + lo;
                int within = col - 1536;
                int h = within >> 6, d = within & 63;
                int l0 = row0 & (L_SEQ - 1), b = row0 >> 11;
                unsigned w0, w1;
                asm("v_cvt_pk_bf16_f32 %0, %1, %2" : "=v"(w0) : "v"(acc[mi][nj][0]), "v"(acc[mi][nj][1]));
                asm("v_cvt_pk_bf16_f32 %0, %1, %2" : "=v"(w1) : "v"(acc[mi][nj][2]), "v"(acc[mi][nj][3]));
                uint2 pk2; pk2.x = w0; pk2.y = w1;
                *(uint2*)(vt + (((size_t)(b * NHEAD + h)) * 64 + d) * L_SEQ + l0) = pk2;
            }
    } else {
#pragma unroll
        for (int mi = 0; mi < 4; mi++)
#pragma unroll
            for (int nj = 0; nj < 4; nj++)
#pragma unroll
                for (int i = 0; i < 4; i++) {
                    int row = bm + wrow + mi * 16 + hi * 4 + i;
                    int col = bn + wcol + nj * 16 + lo;
                    float v = acc[mi][nj][i];
                    int within = col - which * 768;
                    int h = within >> 6, d = within & 63;
                    int l = row & (L_SEQ - 1), b = row >> 11;
                    int dp = d >> 1;
                    float cc = fc[l * 32 + dp], sn = fs[l * 32 + dp];
                    float pv = __shfl_xor(v, 1);
                    float r_;
                    if ((lo & 1) == 0) r_ = v * cc - pv * sn;   // even d
                    else               r_ = pv * sn + v * cc;   // odd d
                    if (which == 0) r_ *= QSCALE;
                    u16* dst = (which == 0) ? qo : ko;
                    dst[(((size_t)(b * NHEAD + h)) * L_SEQ + l) * 64 + d] = f2bf(r_);
                }
    }
}

// ---------------- generic BK=64 GEMM, residual epilogue ----------------------------
// MODE 0: X fp32, out bf16  (O-proj -> ybuf bf16)
// MODE 1: X bf16, out fp32  (final -> d_out fp32)
template<int MODE>
__global__ __launch_bounds__(256) void gemm_res64(
    const u16* __restrict__ A, const u16* __restrict__ Bt,
    void* __restrict__ outp, const void* __restrict__ X, const float* __restrict__ coef,
    int M, int N, int K)
{
    __shared__ __align__(16) u16 As[2][64 * 64];
    __shared__ __align__(16) u16 Bs[2][128 * 64];
    const int tid = threadIdx.x;
    const int lane = tid & 63, wid = tid >> 6;
    const int lo = lane & 15, hi = lane >> 4;
    const int bm = blockIdx.x * 64, bn = blockIdx.y * 128;
    const int wrow = (wid >> 1) * 32, wcol = (wid & 1) * 64;

    f32x4 acc[2][4];
#pragma unroll
    for (int a = 0; a < 2; a++)
#pragma unroll
        for (int b = 0; b < 4; b++)
            acc[a][b] = (f32x4){0.f, 0.f, 0.f, 0.f};

    auto stage = [&](int buf, int k0) {
#pragma unroll
        for (int p = 0; p < 2; p++) {
            int ch = tid + p * 256;
            int r = ch >> 3, g = ch & 7;
            gload16(A + (size_t)(bm + r) * K + k0 + ((g ^ (r & 7)) * 8), &As[buf][ch * 8]);
        }
#pragma unroll
        for (int p = 0; p < 4; p++) {
            int ch = tid + p * 256;
            int r = ch >> 3, g = ch & 7;
            gload16(Bt + (size_t)(bn + r) * K + k0 + ((g ^ (r & 7)) * 8), &Bs[buf][ch * 8]);
        }
    };

    stage(0, 0);
    int cur = 0;
    const int NT = K >> 6;
    for (int t = 0; t < NT; t++) {
        __syncthreads();
        if (t + 1 < NT) stage(cur ^ 1, (t + 1) * 64);
        short8 af[2][2], bfr[4][2];
#pragma unroll
        for (int mi = 0; mi < 2; mi++) {
            int r = wrow + mi * 16 + lo;
#pragma unroll
            for (int h = 0; h < 2; h++)
                af[mi][h] = *(const short8*)(&As[cur][r * 64 + (((h * 4 + hi) ^ (r & 7)) * 8)]);
        }
#pragma unroll
        for (int nj = 0; nj < 4; nj++) {
            int r = wcol + nj * 16 + lo;
#pragma unroll
            for (int h = 0; h < 2; h++)
                bfr[nj][h] = *(const short8*)(&Bs[cur][r * 64 + (((h * 4 + hi) ^ (r & 7)) * 8)]);
        }
        __builtin_amdgcn_s_setprio(1);
#pragma unroll
        for (int mi = 0; mi < 2; mi++)
#pragma unroll
            for (int nj = 0; nj < 4; nj++) {
                acc[mi][nj] = __builtin_amdgcn_mfma_f32_16x16x32_bf16(af[mi][0], bfr[nj][0], acc[mi][nj], 0, 0, 0);
                acc[mi][nj] = __builtin_amdgcn_mfma_f32_16x16x32_bf16(af[mi][1], bfr[nj][1], acc[mi][nj], 0, 0, 0);
            }
        __builtin_amdgcn_s_setprio(0);
        cur ^= 1;
    }
#pragma unroll
    for (int mi = 0; mi < 2; mi++)
#pragma unroll
        for (int nj = 0; nj < 4; nj++)
#pragma unroll
            for (int i = 0; i < 4; i++) {
                int row = bm + wrow + mi * 16 + hi * 4 + i;
                int col = bn + wcol + nj * 16 + lo;
                size_t idx = (size_t)row * N + col;
                int b = row >> 11;
                float base = (MODE == 0) ? ((const float*)X)[idx]
                                         : bf2f(((const u16*)X)[idx]);
                float v = base + acc[mi][nj][i] * coef[(size_t)b * N + col];
                if (MODE == 0) ((u16*)outp)[idx] = f2bf(v);
                else           ((float*)outp)[idx] = v;
            }
}

// ---------------- fused FFN1, BK=64: ff = bf16(silu(A@G^T) * (A@H^T)) --------------
__global__ __launch_bounds__(256) void gemm_ffn1(
    const u16* __restrict__ A, const u16* __restrict__ Gt, const u16* __restrict__ Ht,
    u16* __restrict__ ff, int M, int N, int K)
{
    __shared__ __align__(16) u16 As[2][128 * 64];
    __shared__ __align__(16) u16 Gs[2][64 * 64];
    __shared__ __align__(16) u16 Hs[2][64 * 64];
    const int tid = threadIdx.x;
    const int lane = tid & 63, wid = tid >> 6;
    const int lo = lane & 15, hi = lane >> 4;
    const int bm = blockIdx.x * 128, bn = blockIdx.y * 64;
    const int wrow = (wid >> 1) * 64, wcol = (wid & 1) * 32;

    f32x4 ag[4][2], ah[4][2];
#pragma unroll
    for (int a = 0; a < 4; a++)
#pragma unroll
        for (int b = 0; b < 2; b++) {
            ag[a][b] = (f32x4){0.f, 0.f, 0.f, 0.f};
            ah[a][b] = (f32x4){0.f, 0.f, 0.f, 0.f};
        }

    auto stage = [&](int buf, int k0) {
#pragma unroll
        for (int p = 0; p < 4; p++) {
            int ch = tid + p * 256;
            int r = ch >> 3, g = ch & 7;
            gload16(A + (size_t)(bm + r) * K + k0 + ((g ^ (r & 7)) * 8), &As[buf][ch * 8]);
        }
#pragma unroll
        for (int p = 0; p < 2; p++) {
            int ch = tid + p * 256;
            int r = ch >> 3, g = ch & 7;
            gload16(Gt + (size_t)(bn + r) * K + k0 + ((g ^ (r & 7)) * 8), &Gs[buf][ch * 8]);
        }
#pragma unroll
        for (int p = 0; p < 2; p++) {
            int ch = tid + p * 256;
            int r = ch >> 3, g = ch & 7;
            gload16(Ht + (size_t)(bn + r) * K + k0 + ((g ^ (r & 7)) * 8), &Hs[buf][ch * 8]);
        }
    };

    stage(0, 0);
    int cur = 0;
    const int NT = K >> 6;
    for (int t = 0; t < NT; t++) {
        __syncthreads();
        if (t + 1 < NT) stage(cur ^ 1, (t + 1) * 64);
        short8 af[4][2], gf[2][2], hf[2][2];
#pragma unroll
        for (int mi = 0; mi < 4; mi++) {
            int r = wrow + mi * 16 + lo;
#pragma unroll
            for (int h = 0; h < 2; h++)
                af[mi][h] = *(const short8*)(&As[cur][r * 64 + (((h * 4 + hi) ^ (r & 7)) * 8)]);
        }
#pragma unroll
        for (int nj = 0; nj < 2; nj++) {
            int r = wcol + nj * 16 + lo;
#pragma unroll
            for (int h = 0; h < 2; h++) {
                gf[nj][h] = *(const short8*)(&Gs[cur][r * 64 + (((h * 4 + hi) ^ (r & 7)) * 8)]);
                hf[nj][h] = *(const short8*)(&Hs[cur][r * 64 + (((h * 4 + hi) ^ (r & 7)) * 8)]);
            }
        }
        __builtin_amdgcn_s_setprio(1);
#pragma unroll
        for (int mi = 0; mi < 4; mi++)
#pragma unroll
            for (int nj = 0; nj < 2; nj++) {
                ag[mi][nj] = __builtin_amdgcn_mfma_f32_16x16x32_bf16(af[mi][0], gf[nj][0], ag[mi][nj], 0, 0, 0);
                ag[mi][nj] = __builtin_amdgcn_mfma_f32_16x16x32_bf16(af[mi][1], gf[nj][1], ag[mi][nj], 0, 0, 0);
                ah[mi][nj] = __builtin_amdgcn_mfma_f32_16x16x32_bf16(af[mi][0], hf[nj][0], ah[mi][nj], 0, 0, 0);
                ah[mi][nj] = __builtin_amdgcn_mfma_f32_16x16x32_bf16(af[mi][1], hf[nj][1], ah[mi][nj], 0, 0, 0);
            }
        __builtin_amdgcn_s_setprio(0);
        cur ^= 1;
    }
#pragma unroll
    for (int mi = 0; mi < 4; mi++)
#pragma unroll
        for (int nj = 0; nj < 2; nj++)
#pragma unroll
            for (int i = 0; i < 4; i++) {
                int row = bm + wrow + mi * 16 + hi * 4 + i;
                int col = bn + wcol + nj * 16 + lo;
                ff[(size_t)row * N + col] = f2bf(silu_f(ag[mi][nj][i]) * ah[mi][nj][i]);
            }
}

// ---------------- flash attention: 512 threads (8 waves), QBLK=128, KVB=128 --------
__global__ __launch_bounds__(512) void attn_fwd(
    const u16* __restrict__ q, const u16* __restrict__ k, const u16* __restrict__ vt,
    u16* __restrict__ outp)
{
    __shared__ __align__(16) u16 Kb[KVB * 64];      // 16 KB
    __shared__ __align__(16) u16 Vb[64 * KVB];      // 16 KB
    __shared__ __align__(16) u16 Ps[8][16 * KVB];   // 32 KB
    const int tid = threadIdx.x;
    const int lane = tid & 63, wid = tid >> 6;      // 8 waves
    const int lo = lane & 15, hi = lane >> 4;
    const int lid = blockIdx.x;
    const int xcd = lid & 7, li = lid >> 3;          // li 0..47
    const int bh = xcd * 3 + (li >> 4);              // 3 heads per XCD
    const int qt = li & 15;                          // 16 q-tiles of 128
    const int b = bh / NHEAD, h = bh % NHEAD;
    const int q0 = qt * QBLK + wid * 16;
    const u16* qb = q + ((size_t)bh * L_SEQ + q0) * 64;
    const u16* kbase = k + (size_t)bh * L_SEQ * 64;
    const u16* vbase = vt + (size_t)bh * 64 * L_SEQ;

    short8 qa0 = *(const short8*)(qb + lo * 64 + hi * 8);
    short8 qa1 = *(const short8*)(qb + lo * 64 + 32 + hi * 8);

    f32x4 oacc[4];
#pragma unroll
    for (int dt = 0; dt < 4; dt++) oacc[dt] = (f32x4){0.f, 0.f, 0.f, 0.f};
    float m_ = -1e30f, ls = 0.f;

    const int rk = tid >> 3, gk = tid & 7;
    const u16* ka = kbase + (size_t)rk * 64 + ((gk ^ (rk & 7)) * 8);
    const int rv = tid >> 4, gv = tid & 15;
    const u16* va = vbase + (size_t)rv * L_SEQ + ((gv ^ (rv & 15)) * 8);
    u16* kdst = &Kb[tid * 8];
    u16* vdst = &Vb[tid * 8];

    int4 kr0, kr1, vr0, vr1;
    kr0 = *(const int4*)(ka);
    kr1 = *(const int4*)(ka + 4096);
    vr0 = *(const int4*)(va);
    vr1 = *(const int4*)(va + 65536);

    const int NT = L_SEQ / KVB;   // 16
    u16* pw = &Ps[wid][0];
    const int pkey = lo << 3;
    for (int t = 0; t < NT; t++) {
        __syncthreads();
        *(int4*)(kdst)        = kr0;
        *(int4*)(kdst + 4096) = kr1;
        *(int4*)(vdst)        = vr0;
        *(int4*)(vdst + 4096) = vr1;
        __syncthreads();
        if (t + 1 < NT) {
            int kv0 = (t + 1) * KVB;
            const u16* kan = ka + (size_t)kv0 * 64;
            const u16* van = va + kv0;
            kr0 = *(const int4*)(kan);
            kr1 = *(const int4*)(kan + 4096);
            vr0 = *(const int4*)(van);
            vr1 = *(const int4*)(van + 65536);
        }
        f32x4 s[8];
#pragma unroll
        for (int nt = 0; nt < 8; nt++) {
            int kr_ = nt * 16 + lo;
            const u16* kp = &Kb[kr_ * 64];
            int key = (kr_ & 7) << 3;
            short8 kf0 = *(const short8*)(kp + ((hi * 8) ^ key));
            short8 kf1 = *(const short8*)(kp + ((32 + hi * 8) ^ key));
            __builtin_amdgcn_s_setprio(1);
            f32x4 z = (f32x4){0.f, 0.f, 0.f, 0.f};
            z = __builtin_amdgcn_mfma_f32_16x16x32_bf16(kf0, qa0, z, 0, 0, 0);
            s[nt] = __builtin_amdgcn_mfma_f32_16x16x32_bf16(kf1, qa1, s[nt] = z, 0, 0, 0);
            __builtin_amdgcn_s_setprio(0);
        }
        float t0 = fmaxf(fmaxf(s[0][0], s[0][1]), fmaxf(s[0][2], s[0][3]));
        float t1 = fmaxf(fmaxf(s[1][0], s[1][1]), fmaxf(s[1][2], s[1][3]));
        float t2 = fmaxf(fmaxf(s[2][0], s[2][1]), fmaxf(s[2][2], s[2][3]));
        float t3 = fmaxf(fmaxf(s[3][0], s[3][1]), fmaxf(s[3][2], s[3][3]));
        float t4 = fmaxf(fmaxf(s[4][0], s[4][1]), fmaxf(s[4][2], s[4][3]));
        float t5 = fmaxf(fmaxf(s[5][0], s[5][1]), fmaxf(s[5][2], s[5][3]));
        float t6 = fmaxf(fmaxf(s[6][0], s[6][1]), fmaxf(s[6][2], s[6][3]));
        float t7 = fmaxf(fmaxf(s[7][0], s[7][1]), fmaxf(s[7][2], s[7][3]));
        float pmax = fmaxf(fmaxf(fmaxf(t0, t1), fmaxf(t2, t3)),
                           fmaxf(fmaxf(t4, t5), fmaxf(t6, t7)));
        pmax = fmaxf(pmax, __shfl_xor(pmax, 16));
        pmax = fmaxf(pmax, __shfl_xor(pmax, 32));
        if (!__all(pmax - m_ <= 8.f)) {
            float mn = fmaxf(m_, pmax);
            float al = exp2f(m_ - mn);
            m_ = mn;
            ls *= al;
#pragma unroll
            for (int dt = 0; dt < 4; dt++) oacc[dt] *= al;
        }
        float rsA = 0.f, rsB = 0.f, rsC = 0.f, rsD = 0.f;
#pragma unroll
        for (int nt = 0; nt < 8; nt++) {
            float p0 = exp2f(s[nt][0] - m_);
            float p1 = exp2f(s[nt][1] - m_);
            float p2 = exp2f(s[nt][2] - m_);
            float p3 = exp2f(s[nt][3] - m_);
            s[nt][0] = p0; s[nt][1] = p1; s[nt][2] = p2; s[nt][3] = p3;
            rsA += p0; rsB += p1; rsC += p2; rsD += p3;
        }
        ls += (rsA + rsB) + (rsC + rsD);
#pragma unroll
        for (int nt = 0; nt < 8; nt++) {
            unsigned w0, w1;
            asm("v_cvt_pk_bf16_f32 %0, %1, %2" : "=v"(w0) : "v"(s[nt][0]), "v"(s[nt][1]));
            asm("v_cvt_pk_bf16_f32 %0, %1, %2" : "=v"(w1) : "v"(s[nt][2]), "v"(s[nt][3]));
            uint2 pk2; pk2.x = w0; pk2.y = w1;
            *(uint2*)(pw + lo * KVB + ((nt * 16 + hi * 4) ^ pkey)) = pk2;
        }
        short8 pa0 = *(const short8*)(pw + lo * KVB + ((0 * 32 + hi * 8) ^ pkey));
        short8 pa1 = *(const short8*)(pw + lo * KVB + ((1 * 32 + hi * 8) ^ pkey));
        short8 pa2 = *(const short8*)(pw + lo * KVB + ((2 * 32 + hi * 8) ^ pkey));
        short8 pa3 = *(const short8*)(pw + lo * KVB + ((3 * 32 + hi * 8) ^ pkey));
#pragma unroll
        for (int dt = 0; dt < 4; dt++) {
            int vr_ = dt * 16 + lo;
            const u16* vp = &Vb[vr_ * KVB];
            int vkey = (vr_ & 15) << 3;
            short8 vf0 = *(const short8*)(vp + ((0 * 32 + hi * 8) ^ vkey));
            short8 vf1 = *(const short8*)(vp + ((1 * 32 + hi * 8) ^ vkey));
            short8 vf2 = *(const short8*)(vp + ((2 * 32 + hi * 8) ^ vkey));
            short8 vf3 = *(const short8*)(vp + ((3 * 32 + hi * 8) ^ vkey));
            __builtin_amdgcn_s_setprio(1);
            oacc[dt] = __builtin_amdgcn_mfma_f32_16x16x32_bf16(vf0, pa0, oacc[dt], 0, 0, 0);
            oacc[dt] = __builtin_amdgcn_mfma_f32_16x16x32_bf16(vf1, pa1, oacc[dt], 0, 0, 0);
            oacc[dt] = __builtin_amdgcn_mfma_f32_16x16x32_bf16(vf2, pa2, oacc[dt], 0, 0, 0);
            oacc[dt] = __builtin_amdgcn_mfma_f32_16x16x32_bf16(vf3, pa3, oacc[dt], 0, 0, 0);
            __builtin_amdgcn_s_setprio(0);
        }
    }
    ls += __shfl_xor(ls, 16);
    ls += __shfl_xor(ls, 32);
    float inv = 1.f / ls;
    int qrow = q0 + lo;
    u16* orow = outp + ((size_t)(b * L_SEQ + qrow)) * 768 + h * 64;
#pragma unroll
    for (int dt = 0; dt < 4; dt++) {
        unsigned w0, w1;
        float o0 = oacc[dt][0] * inv, o1 = oacc[dt][1] * inv;
        float o2 = oacc[dt][2] * inv, o3 = oacc[dt][3] * inv;
        asm("v_cvt_pk_bf16_f32 %0, %1, %2" : "=v"(w0) : "v"(o0), "v"(o1));
        asm("v_cvt_pk_bf16_f32 %0, %1, %2" : "=v"(w1) : "v"(o2), "v"(o3));
        uint2 pk2; pk2.x = w0; pk2.y = w1;
        *(uint2*)(orow + dt * 16 + hi * 4) = pk2;
    }
}

extern "C" void kernel_launch(void* const* d_in, const int* in_sizes, int n_in,
                              void* d_out, int out_size, void* d_ws, size_t ws_size,
                              hipStream_t stream)
{
    const float* x      = (const float*)d_in[0];
    const float* c      = (const float*)d_in[1];
    const float* fcos   = (const float*)d_in[2];
    const float* fsin   = (const float*)d_in[3];
    const float* Wq     = (const float*)d_in[4];
    const float* Wk     = (const float*)d_in[5];
    const float* Wv     = (const float*)d_in[6];
    const float* Wo     = (const float*)d_in[7];
    const float* cw1    = (const float*)d_in[8];
    const float* cb1    = (const float*)d_in[9];
    const float* cw2    = (const float*)d_in[10];
    const float* cb2    = (const float*)d_in[11];
    const float* anw    = (const float*)d_in[12];
    const float* Walpha = (const float*)d_in[13];
    const float* Wbeta  = (const float*)d_in[14];
    const float* Wgamma = (const float*)d_in[15];
    const float* Wgate  = (const float*)d_in[16];
    const float* Whid   = (const float*)d_in[17];
    const float* Wout   = (const float*)d_in[18];
    const float* fnw    = (const float*)d_in[19];
    const float* Wbetaf = (const float*)d_in[20];
    const float* Wgammaf= (const float*)d_in[21];

    const int M = 4096; // B*L
    char* ws = (char*)d_ws;
    size_t off = 0;
    auto alloc = [&](size_t bytes) -> char* {
        char* p = ws + off;
        off += (bytes + 255) & ~(size_t)255;
        return p;
    };
    u16* wq_t   = (u16*)alloc((size_t)768 * 768 * 2);
    u16* wk_t   = (u16*)alloc((size_t)768 * 768 * 2);
    u16* wv_t   = (u16*)alloc((size_t)768 * 768 * 2);
    u16* wo_t   = (u16*)alloc((size_t)768 * 768 * 2);
    u16* gate_t = (u16*)alloc((size_t)3072 * 768 * 2);
    u16* hid_t  = (u16*)alloc((size_t)3072 * 768 * 2);
    u16* out_t  = (u16*)alloc((size_t)768 * 3072 * 2);
    float* part1 = (float*)alloc((size_t)8 * 2 * 3072 * 4);
    float* part2 = (float*)alloc((size_t)8 * 2 * 768 * 4);
    float* mods = (float*)alloc(5 * 2 * 768 * 4);
    u16* hbuf   = (u16*)alloc((size_t)M * 768 * 2);
    u16* qrope  = (u16*)alloc((size_t)M * 768 * 2);
    u16* krope  = (u16*)alloc((size_t)M * 768 * 2);
    u16* vtb    = (u16*)alloc((size_t)M * 768 * 2);
    u16* attnh  = (u16*)alloc((size_t)M * 768 * 2);
    u16* ybuf   = (u16*)alloc((size_t)M * 768 * 2);
    u16* ffbuf  = (u16*)alloc((size_t)M * 3072 * 2);

    // 1. ALL weight transposes in one launch
    transpose_all<<<9216, 256, 0, stream>>>(
        Wq, Wk, Wv, Wo, Wgate, Whid, Wout,
        wq_t, wk_t, wv_t, wo_t, gate_t, hid_t, out_t);

    // 2. conditioning path
    cond_mlp1<<<dim3(12, 8), 256, 0, stream>>>(c, cw1, part1);
    cond_mlp2<<<dim3(12, 8), 256, 0, stream>>>(part1, cb1, cw2, part2);
    mod_gemm<<<dim3(12, 5), 256, 0, stream>>>(
        part2, cb2, Wgamma, Wbeta, Walpha, Wgammaf, Wbetaf, mods);

    // 3. h = rms(x)*gamma_a + beta_a (fp32 input)
    rmsnorm_mod<0><<<M, 256, 0, stream>>>(x, anw, mods + 0 * 1536, mods + 1 * 1536, hbuf);

    // 4. fused QKV GEMM + RoPE + V-transpose epilogue
    gemm_qkv_rope<<<dim3(32, 18), 256, 0, stream>>>(
        hbuf, wq_t, fcos, fsin, qrope, krope, vtb, M, 2304, 768);

    // 5. attention -> attnh (B,L,D) bf16
    attn_fwd<<<dim3(384), 512, 0, stream>>>(qrope, krope, vtb, attnh);

    // 6. O-proj + residual: ybuf(bf16) = x + (attnh @ Wo) * alpha_a
    gemm_res64<0><<<dim3(64, 6), 256, 0, stream>>>(
        attnh, wo_t, ybuf, x, mods + 2 * 1536, M, 768, 768);

    // 7. h2 = rms(y)*gamma_f + beta_f (bf16 input)
    rmsnorm_mod<1><<<M, 256, 0, stream>>>(ybuf, fnw, mods + 3 * 1536, mods + 4 * 1536, hbuf);

    // 8. fused gate/hidden GEMM + silu-mul -> ffbuf
    gemm_ffn1<<<dim3(32, 48), 256, 0, stream>>>(
        hbuf, gate_t, hid_t, ffbuf, M, 3072, 768);

    // 9. out(fp32) = y(bf16) + (ff @ Wout) * gamma_f
    gemm_res64<1><<<dim3(64, 6), 256, 0, stream>>>(
        ffbuf, out_t, d_out, ybuf, mods + 3 * 1536, M, 768, 3072);
}

// Round 19
// 243.736 us; speedup vs baseline: 1.0754x; 1.0072x over previous
//
#include <hip/hip_runtime.h>

typedef unsigned short u16;
typedef __attribute__((ext_vector_type(8))) short short8;
typedef __attribute__((ext_vector_type(4))) float f32x4;

#define L_SEQ 2048
#define NHEAD 12
#define KVB 128
#define QBLK 128

__device__ __forceinline__ u16 f2bf(float f) {
    union { float f; unsigned u; } x; x.f = f;
    unsigned r = x.u + 0x7fffu + ((x.u >> 16) & 1u);
    return (u16)(r >> 16);
}
__device__ __forceinline__ float bf2f(u16 u) {
    union { unsigned u; float f; } x; x.u = ((unsigned)u) << 16;
    return x.f;
}
__device__ __forceinline__ float silu_f(float x) { return x / (1.f + __expf(-x)); }

// async global->LDS, 16B per lane. LDS dest must be wave-uniform base + lane*16.
__device__ __forceinline__ void gload16(const u16* g, u16* l) {
    __builtin_amdgcn_global_load_lds(
        (const __attribute__((address_space(1))) void*)g,
        (__attribute__((address_space(3))) void*)l, 16, 0, 0);
}

// ---------------- ALL weight transposes in one launch: W(K,N) -> Wt(N,K) -----------
__global__ __launch_bounds__(256) void transpose_all(
    const float* __restrict__ S0, const float* __restrict__ S1,
    const float* __restrict__ S2, const float* __restrict__ S3,
    const float* __restrict__ S4, const float* __restrict__ S5,
    const float* __restrict__ S6,
    u16* __restrict__ D0, u16* __restrict__ D1, u16* __restrict__ D2,
    u16* __restrict__ D3, u16* __restrict__ D4, u16* __restrict__ D5,
    u16* __restrict__ D6)
{
    int id = blockIdx.x;
    const float* W; u16* Wt; int K, N, local;
    if (id < 2304) {
        int sec = id / 576; local = id - sec * 576; K = 768; N = 768;
        W  = (sec == 0) ? S0 : (sec == 1) ? S1 : (sec == 2) ? S2 : S3;
        Wt = (sec == 0) ? D0 : (sec == 1) ? D1 : (sec == 2) ? D2 : D3;
    } else if (id < 6912) {
        int sec = (id - 2304) / 2304; local = (id - 2304) - sec * 2304; K = 768; N = 3072;
        W = sec ? S5 : S4; Wt = sec ? D5 : D4;
    } else {
        local = id - 6912; K = 3072; N = 768; W = S6; Wt = D6;
    }
    int nx = N >> 5;
    int n0 = (local % nx) * 32, k0 = (local / nx) * 32;
    __shared__ float t[32][33];
    int tx = threadIdx.x & 31, ty = threadIdx.x >> 5; // ty 0..7
#pragma unroll
    for (int i = 0; i < 4; i++)
        t[ty + 8 * i][tx] = W[(size_t)(k0 + ty + 8 * i) * N + n0 + tx];
    __syncthreads();
#pragma unroll
    for (int i = 0; i < 4; i++)
        Wt[(size_t)(n0 + ty + 8 * i) * K + k0 + tx] = f2bf(t[tx][ty + 8 * i]);
}

// ---------------- cond MLP layer 1, K-split ----------
__global__ __launch_bounds__(256) void cond_mlp1(
    const float* __restrict__ c, const float* __restrict__ w1, float* __restrict__ part)
{
    int j = blockIdx.x * 256 + threadIdx.x; // 0..3071
    int d0 = blockIdx.y * 96;
    float a0 = 0.f, a1 = 0.f;
    for (int d = d0; d < d0 + 96; ++d) {
        float w = w1[(size_t)d * 3072 + j];
        a0 += c[d] * w;
        a1 += c[768 + d] * w;
    }
    part[(size_t)(blockIdx.y * 2 + 0) * 3072 + j] = a0;
    part[(size_t)(blockIdx.y * 2 + 1) * 3072 + j] = a1;
}

// ---------------- cond MLP layer 2, K-split ----------
__global__ __launch_bounds__(256) void cond_mlp2(
    const float* __restrict__ part, const float* __restrict__ b1,
    const float* __restrict__ w2, float* __restrict__ c2part)
{
    __shared__ float hid[2][384];
    const int tid = threadIdx.x;
    const int d0 = blockIdx.y * 384;
    for (int i = tid; i < 768; i += 256) {
        int b = i / 384, dd = i - b * 384;
        float s = b1[d0 + dd];
#pragma unroll
        for (int p = 0; p < 8; p++) s += part[(size_t)(p * 2 + b) * 3072 + d0 + dd];
        hid[b][dd] = silu_f(s);
    }
    __syncthreads();
    int jj = tid & 63, kc = tid >> 6;
    int j = blockIdx.x * 64 + jj;
    float a0 = 0.f, a1 = 0.f;
    for (int dd = kc * 96; dd < kc * 96 + 96; ++dd) {
        float w = w2[(size_t)(d0 + dd) * 768 + j];
        a0 += hid[0][dd] * w;
        a1 += hid[1][dd] * w;
    }
    __shared__ float r0[256], r1[256];
    r0[tid] = a0; r1[tid] = a1;
    __syncthreads();
    if (kc == 0) {
        a0 = r0[jj] + r0[64 + jj] + r0[128 + jj] + r0[192 + jj];
        a1 = r1[jj] + r1[64 + jj] + r1[128 + jj] + r1[192 + jj];
        c2part[(size_t)(blockIdx.y * 2 + 0) * 768 + j] = a0;
        c2part[(size_t)(blockIdx.y * 2 + 1) * 768 + j] = a1;
    }
}

// ---------------- 5 modulation vectors ----------
__global__ __launch_bounds__(256) void mod_gemm(
    const float* __restrict__ c2part, const float* __restrict__ b2,
    const float* __restrict__ W0, const float* __restrict__ W1,
    const float* __restrict__ W2, const float* __restrict__ W3,
    const float* __restrict__ W4, float* __restrict__ out)
{
    __shared__ float c2s[2][768];
    const int tid = threadIdx.x;
    for (int i = tid; i < 1536; i += 256) {
        int b = i / 768, d = i - b * 768;
        float s = b2[d];
#pragma unroll
        for (int p = 0; p < 8; p++) s += c2part[(size_t)(p * 2 + b) * 768 + d];
        c2s[b][d] = s;
    }
    __syncthreads();
    int w = blockIdx.y;
    const float* W = (w == 0) ? W0 : (w == 1) ? W1 : (w == 2) ? W2 : (w == 3) ? W3 : W4;
    int jj = tid & 63, kc = tid >> 6; // 4 k-chunks of 192
    int j = blockIdx.x * 64 + jj;
    float a0 = 0.f, a1 = 0.f;
    for (int d = kc * 192; d < kc * 192 + 192; ++d) {
        float ww = W[(size_t)d * 768 + j];
        a0 += c2s[0][d] * ww;
        a1 += c2s[1][d] * ww;
    }
    __shared__ float r0[256], r1[256];
    r0[tid] = a0; r1[tid] = a1;
    __syncthreads();
    if (kc == 0) {
        a0 = r0[jj] + r0[64 + jj] + r0[128 + jj] + r0[192 + jj];
        a1 = r1[jj] + r1[64 + jj] + r1[128 + jj] + r1[192 + jj];
        out[(size_t)(w * 2 + 0) * 768 + j] = a0;
        out[(size_t)(w * 2 + 1) * 768 + j] = a1;
    }
}

// ---------------- fused RMSNorm * gamma_mod + beta_mod -> bf16 ----------
// IN==0: fp32 input; IN==1: bf16 input.
template<int IN>
__global__ __launch_bounds__(256) void rmsnorm_mod(
    const void* __restrict__ xin, const float* __restrict__ nw,
    const float* __restrict__ gamma, const float* __restrict__ beta,
    u16* __restrict__ hout)
{
    int row = blockIdx.x;      // 0..4095
    int b = row >> 11;         // L=2048
    int t = threadIdx.x;
    float v0, v1, v2;
    if (IN == 0) {
        const float* xr = (const float*)xin + (size_t)row * 768;
        v0 = xr[t]; v1 = xr[t + 256]; v2 = xr[t + 512];
    } else {
        const u16* xr = (const u16*)xin + (size_t)row * 768;
        v0 = bf2f(xr[t]); v1 = bf2f(xr[t + 256]); v2 = bf2f(xr[t + 512]);
    }
    float ss = v0 * v0 + v1 * v1 + v2 * v2;
#pragma unroll
    for (int m = 1; m < 64; m <<= 1) ss += __shfl_xor(ss, m);
    __shared__ float red[4];
    if ((t & 63) == 0) red[t >> 6] = ss;
    __syncthreads();
    float tot = red[0] + red[1] + red[2] + red[3];
    float rr = rsqrtf(tot * (1.f / 768.f) + 1e-6f);
    u16* ho = hout + (size_t)row * 768;
    const float* g = gamma + (size_t)b * 768;
    const float* be = beta + (size_t)b * 768;
#pragma unroll
    for (int i = 0; i < 3; i++) {
        int col = t + i * 256;
        float v = (i == 0) ? v0 : (i == 1) ? v1 : v2;
        ho[col] = f2bf(v * rr * nw[col] * g[col] + be[col]);
    }
}

// ===================== BK=64 swizzled-LDS GEMM family ==============================
// LDS tile rows are 64 u16 (128B); granule (16B) swizzle: LDS[r][g] holds source
// granule g^(r&7) (same involution staged and read -> bank-conflict-free).
// NOTE (R19): s_setprio removed from all GEMM kernels — T5 is null/negative on
// lockstep 2-phase barrier-synced GEMM structures (catalog m190); kept in attn.

// ---------------- QKV GEMM + fused RoPE + V-transpose epilogue ---------------------
// Q cols [0,768): rope*QSCALE -> qo(B,H,L,64). K cols [768,1536): rope -> ko.
// V cols [1536,2304): directly transposed -> vt(B,H,64,L) via packed 8B stores.
__global__ __launch_bounds__(256) void gemm_qkv_rope(
    const u16* __restrict__ A, const u16* __restrict__ Bt,
    const float* __restrict__ fc, const float* __restrict__ fs,
    u16* __restrict__ qo, u16* __restrict__ ko, u16* __restrict__ vt,
    int M, int N, int K)
{
    const float QSCALE = 0.125f * 1.44269504f;
    __shared__ __align__(16) u16 As[2][128 * 64];
    __shared__ __align__(16) u16 Bs[2][128 * 64];
    const int tid = threadIdx.x;
    const int lane = tid & 63, wid = tid >> 6;
    const int lo = lane & 15, hi = lane >> 4;
    const int bm = blockIdx.x * 128, bn = blockIdx.y * 128;
    const int wrow = (wid >> 1) * 64, wcol = (wid & 1) * 64;

    f32x4 acc[4][4];
#pragma unroll
    for (int a = 0; a < 4; a++)
#pragma unroll
        for (int b = 0; b < 4; b++)
            acc[a][b] = (f32x4){0.f, 0.f, 0.f, 0.f};

    auto stage = [&](int buf, int k0) {
#pragma unroll
        for (int p = 0; p < 4; p++) {
            int ch = tid + p * 256;
            int r = ch >> 3, g = ch & 7;
            gload16(A + (size_t)(bm + r) * K + k0 + ((g ^ (r & 7)) * 8), &As[buf][ch * 8]);
        }
#pragma unroll
        for (int p = 0; p < 4; p++) {
            int ch = tid + p * 256;
            int r = ch >> 3, g = ch & 7;
            gload16(Bt + (size_t)(bn + r) * K + k0 + ((g ^ (r & 7)) * 8), &Bs[buf][ch * 8]);
        }
    };

    stage(0, 0);
    int cur = 0;
    const int NT = K >> 6;   // BK=64
    for (int t = 0; t < NT; t++) {
        __syncthreads();
        if (t + 1 < NT) stage(cur ^ 1, (t + 1) * 64);
        short8 af[4][2], bfr[4][2];
#pragma unroll
        for (int mi = 0; mi < 4; mi++) {
            int r = wrow + mi * 16 + lo;
#pragma unroll
            for (int h = 0; h < 2; h++)
                af[mi][h] = *(const short8*)(&As[cur][r * 64 + (((h * 4 + hi) ^ (r & 7)) * 8)]);
        }
#pragma unroll
        for (int nj = 0; nj < 4; nj++) {
            int r = wcol + nj * 16 + lo;
#pragma unroll
            for (int h = 0; h < 2; h++)
                bfr[nj][h] = *(const short8*)(&Bs[cur][r * 64 + (((h * 4 + hi) ^ (r & 7)) * 8)]);
        }
#pragma unroll
        for (int mi = 0; mi < 4; mi++)
#pragma unroll
            for (int nj = 0; nj < 4; nj++) {
                acc[mi][nj] = __builtin_amdgcn_mfma_f32_16x16x32_bf16(af[mi][0], bfr[nj][0], acc[mi][nj], 0, 0, 0);
                acc[mi][nj] = __builtin_amdgcn_mfma_f32_16x16x32_bf16(af[mi][1], bfr[nj][1], acc[mi][nj], 0, 0, 0);
            }
        cur ^= 1;
    }
    // epilogue: which = 0 Q / 1 K / 2 V (wave-uniform per block since 768 = 6*128)
    const int which = bn / 768;
    if (which == 2) {
        // V: write transposed. Lane holds 4 consecutive l (i=0..3) at fixed d.
#pragma unroll
        for (int mi = 0; mi < 4; mi++)
#pragma unroll
            for (int nj = 0; nj < 4; nj++) {
                int row0 = bm + wrow + mi * 16 + hi * 4;   // l base (mult of 4)
                int col = bn + wcol + nj * 16 + lo;
                int within = col - 1536;
                int h = within >> 6, d = within & 63;
                int l0 = row0 & (L_SEQ - 1), b = row0 >> 11;
                unsigned w0, w1;
                asm("v_cvt_pk_bf16_f32 %0, %1, %2" : "=v"(w0) : "v"(acc[mi][nj][0]), "v"(acc[mi][nj][1]));
                asm("v_cvt_pk_bf16_f32 %0, %1, %2" : "=v"(w1) : "v"(acc[mi][nj][2]), "v"(acc[mi][nj][3]));
                uint2 pk2; pk2.x = w0; pk2.y = w1;
                *(uint2*)(vt + (((size_t)(b * NHEAD + h)) * 64 + d) * L_SEQ + l0) = pk2;
            }
    } else {
#pragma unroll
        for (int mi = 0; mi < 4; mi++)
#pragma unroll
            for (int nj = 0; nj < 4; nj++)
#pragma unroll
                for (int i = 0; i < 4; i++) {
                    int row = bm + wrow + mi * 16 + hi * 4 + i;
                    int col = bn + wcol + nj * 16 + lo;
                    float v = acc[mi][nj][i];
                    int within = col - which * 768;
                    int h = within >> 6, d = within & 63;
                    int l = row & (L_SEQ - 1), b = row >> 11;
                    int dp = d >> 1;
                    float cc = fc[l * 32 + dp], sn = fs[l * 32 + dp];
                    float pv = __shfl_xor(v, 1);
                    float r_;
                    if ((lo & 1) == 0) r_ = v * cc - pv * sn;   // even d
                    else               r_ = pv * sn + v * cc;   // odd d
                    if (which == 0) r_ *= QSCALE;
                    u16* dst = (which == 0) ? qo : ko;
                    dst[(((size_t)(b * NHEAD + h)) * L_SEQ + l) * 64 + d] = f2bf(r_);
                }
    }
}

// ---------------- generic BK=64 GEMM, residual epilogue ----------------------------
// MODE 0: X fp32, out bf16  (O-proj -> ybuf bf16)
// MODE 1: X bf16, out fp32  (final -> d_out fp32)
template<int MODE>
__global__ __launch_bounds__(256) void gemm_res64(
    const u16* __restrict__ A, const u16* __restrict__ Bt,
    void* __restrict__ outp, const void* __restrict__ X, const float* __restrict__ coef,
    int M, int N, int K)
{
    __shared__ __align__(16) u16 As[2][64 * 64];
    __shared__ __align__(16) u16 Bs[2][128 * 64];
    const int tid = threadIdx.x;
    const int lane = tid & 63, wid = tid >> 6;
    const int lo = lane & 15, hi = lane >> 4;
    const int bm = blockIdx.x * 64, bn = blockIdx.y * 128;
    const int wrow = (wid >> 1) * 32, wcol = (wid & 1) * 64;

    f32x4 acc[2][4];
#pragma unroll
    for (int a = 0; a < 2; a++)
#pragma unroll
        for (int b = 0; b < 4; b++)
            acc[a][b] = (f32x4){0.f, 0.f, 0.f, 0.f};

    auto stage = [&](int buf, int k0) {
#pragma unroll
        for (int p = 0; p < 2; p++) {
            int ch = tid + p * 256;
            int r = ch >> 3, g = ch & 7;
            gload16(A + (size_t)(bm + r) * K + k0 + ((g ^ (r & 7)) * 8), &As[buf][ch * 8]);
        }
#pragma unroll
        for (int p = 0; p < 4; p++) {
            int ch = tid + p * 256;
            int r = ch >> 3, g = ch & 7;
            gload16(Bt + (size_t)(bn + r) * K + k0 + ((g ^ (r & 7)) * 8), &Bs[buf][ch * 8]);
        }
    };

    stage(0, 0);
    int cur = 0;
    const int NT = K >> 6;
    for (int t = 0; t < NT; t++) {
        __syncthreads();
        if (t + 1 < NT) stage(cur ^ 1, (t + 1) * 64);
        short8 af[2][2], bfr[4][2];
#pragma unroll
        for (int mi = 0; mi < 2; mi++) {
            int r = wrow + mi * 16 + lo;
#pragma unroll
            for (int h = 0; h < 2; h++)
                af[mi][h] = *(const short8*)(&As[cur][r * 64 + (((h * 4 + hi) ^ (r & 7)) * 8)]);
        }
#pragma unroll
        for (int nj = 0; nj < 4; nj++) {
            int r = wcol + nj * 16 + lo;
#pragma unroll
            for (int h = 0; h < 2; h++)
                bfr[nj][h] = *(const short8*)(&Bs[cur][r * 64 + (((h * 4 + hi) ^ (r & 7)) * 8)]);
        }
#pragma unroll
        for (int mi = 0; mi < 2; mi++)
#pragma unroll
            for (int nj = 0; nj < 4; nj++) {
                acc[mi][nj] = __builtin_amdgcn_mfma_f32_16x16x32_bf16(af[mi][0], bfr[nj][0], acc[mi][nj], 0, 0, 0);
                acc[mi][nj] = __builtin_amdgcn_mfma_f32_16x16x32_bf16(af[mi][1], bfr[nj][1], acc[mi][nj], 0, 0, 0);
            }
        cur ^= 1;
    }
#pragma unroll
    for (int mi = 0; mi < 2; mi++)
#pragma unroll
        for (int nj = 0; nj < 4; nj++)
#pragma unroll
            for (int i = 0; i < 4; i++) {
                int row = bm + wrow + mi * 16 + hi * 4 + i;
                int col = bn + wcol + nj * 16 + lo;
                size_t idx = (size_t)row * N + col;
                int b = row >> 11;
                float base = (MODE == 0) ? ((const float*)X)[idx]
                                         : bf2f(((const u16*)X)[idx]);
                float v = base + acc[mi][nj][i] * coef[(size_t)b * N + col];
                if (MODE == 0) ((u16*)outp)[idx] = f2bf(v);
                else           ((float*)outp)[idx] = v;
            }
}

// ---------------- fused FFN1, BK=64: ff = bf16(silu(A@G^T) * (A@H^T)) --------------
__global__ __launch_bounds__(256) void gemm_ffn1(
    const u16* __restrict__ A, const u16* __restrict__ Gt, const u16* __restrict__ Ht,
    u16* __restrict__ ff, int M, int N, int K)
{
    __shared__ __align__(16) u16 As[2][128 * 64];
    __shared__ __align__(16) u16 Gs[2][64 * 64];
    __shared__ __align__(16) u16 Hs[2][64 * 64];
    const int tid = threadIdx.x;
    const int lane = tid & 63, wid = tid >> 6;
    const int lo = lane & 15, hi = lane >> 4;
    const int bm = blockIdx.x * 128, bn = blockIdx.y * 64;
    const int wrow = (wid >> 1) * 64, wcol = (wid & 1) * 32;

    f32x4 ag[4][2], ah[4][2];
#pragma unroll
    for (int a = 0; a < 4; a++)
#pragma unroll
        for (int b = 0; b < 2; b++) {
            ag[a][b] = (f32x4){0.f, 0.f, 0.f, 0.f};
            ah[a][b] = (f32x4){0.f, 0.f, 0.f, 0.f};
        }

    auto stage = [&](int buf, int k0) {
#pragma unroll
        for (int p = 0; p < 4; p++) {
            int ch = tid + p * 256;
            int r = ch >> 3, g = ch & 7;
            gload16(A + (size_t)(bm + r) * K + k0 + ((g ^ (r & 7)) * 8), &As[buf][ch * 8]);
        }
#pragma unroll
        for (int p = 0; p < 2; p++) {
            int ch = tid + p * 256;
            int r = ch >> 3, g = ch & 7;
            gload16(Gt + (size_t)(bn + r) * K + k0 + ((g ^ (r & 7)) * 8), &Gs[buf][ch * 8]);
        }
#pragma unroll
        for (int p = 0; p < 2; p++) {
            int ch = tid + p * 256;
            int r = ch >> 3, g = ch & 7;
            gload16(Ht + (size_t)(bn + r) * K + k0 + ((g ^ (r & 7)) * 8), &Hs[buf][ch * 8]);
        }
    };

    stage(0, 0);
    int cur = 0;
    const int NT = K >> 6;
    for (int t = 0; t < NT; t++) {
        __syncthreads();
        if (t + 1 < NT) stage(cur ^ 1, (t + 1) * 64);
        short8 af[4][2], gf[2][2], hf[2][2];
#pragma unroll
        for (int mi = 0; mi < 4; mi++) {
            int r = wrow + mi * 16 + lo;
#pragma unroll
            for (int h = 0; h < 2; h++)
                af[mi][h] = *(const short8*)(&As[cur][r * 64 + (((h * 4 + hi) ^ (r & 7)) * 8)]);
        }
#pragma unroll
        for (int nj = 0; nj < 2; nj++) {
            int r = wcol + nj * 16 + lo;
#pragma unroll
            for (int h = 0; h < 2; h++) {
                gf[nj][h] = *(const short8*)(&Gs[cur][r * 64 + (((h * 4 + hi) ^ (r & 7)) * 8)]);
                hf[nj][h] = *(const short8*)(&Hs[cur][r * 64 + (((h * 4 + hi) ^ (r & 7)) * 8)]);
            }
        }
#pragma unroll
        for (int mi = 0; mi < 4; mi++)
#pragma unroll
            for (int nj = 0; nj < 2; nj++) {
                ag[mi][nj] = __builtin_amdgcn_mfma_f32_16x16x32_bf16(af[mi][0], gf[nj][0], ag[mi][nj], 0, 0, 0);
                ag[mi][nj] = __builtin_amdgcn_mfma_f32_16x16x32_bf16(af[mi][1], gf[nj][1], ag[mi][nj], 0, 0, 0);
                ah[mi][nj] = __builtin_amdgcn_mfma_f32_16x16x32_bf16(af[mi][0], hf[nj][0], ah[mi][nj], 0, 0, 0);
                ah[mi][nj] = __builtin_amdgcn_mfma_f32_16x16x32_bf16(af[mi][1], hf[nj][1], ah[mi][nj], 0, 0, 0);
            }
        cur ^= 1;
    }
#pragma unroll
    for (int mi = 0; mi < 4; mi++)
#pragma unroll
        for (int nj = 0; nj < 2; nj++)
#pragma unroll
            for (int i = 0; i < 4; i++) {
                int row = bm + wrow + mi * 16 + hi * 4 + i;
                int col = bn + wcol + nj * 16 + lo;
                ff[(size_t)row * N + col] = f2bf(silu_f(ag[mi][nj][i]) * ah[mi][nj][i]);
            }
}

// ---------------- flash attention: 512 threads (8 waves), QBLK=128, KVB=128 --------
// setprio kept here (T5 positive on attn structures, m191).
__global__ __launch_bounds__(512) void attn_fwd(
    const u16* __restrict__ q, const u16* __restrict__ k, const u16* __restrict__ vt,
    u16* __restrict__ outp)
{
    __shared__ __align__(16) u16 Kb[KVB * 64];      // 16 KB
    __shared__ __align__(16) u16 Vb[64 * KVB];      // 16 KB
    __shared__ __align__(16) u16 Ps[8][16 * KVB];   // 32 KB
    const int tid = threadIdx.x;
    const int lane = tid & 63, wid = tid >> 6;      // 8 waves
    const int lo = lane & 15, hi = lane >> 4;
    const int lid = blockIdx.x;
    const int xcd = lid & 7, li = lid >> 3;          // li 0..47
    const int bh = xcd * 3 + (li >> 4);              // 3 heads per XCD
    const int qt = li & 15;                          // 16 q-tiles of 128
    const int b = bh / NHEAD, h = bh % NHEAD;
    const int q0 = qt * QBLK + wid * 16;
    const u16* qb = q + ((size_t)bh * L_SEQ + q0) * 64;
    const u16* kbase = k + (size_t)bh * L_SEQ * 64;
    const u16* vbase = vt + (size_t)bh * 64 * L_SEQ;

    short8 qa0 = *(const short8*)(qb + lo * 64 + hi * 8);
    short8 qa1 = *(const short8*)(qb + lo * 64 + 32 + hi * 8);

    f32x4 oacc[4];
#pragma unroll
    for (int dt = 0; dt < 4; dt++) oacc[dt] = (f32x4){0.f, 0.f, 0.f, 0.f};
    float m_ = -1e30f, ls = 0.f;

    const int rk = tid >> 3, gk = tid & 7;
    const u16* ka = kbase + (size_t)rk * 64 + ((gk ^ (rk & 7)) * 8);
    const int rv = tid >> 4, gv = tid & 15;
    const u16* va = vbase + (size_t)rv * L_SEQ + ((gv ^ (rv & 15)) * 8);
    u16* kdst = &Kb[tid * 8];
    u16* vdst = &Vb[tid * 8];

    int4 kr0, kr1, vr0, vr1;
    kr0 = *(const int4*)(ka);
    kr1 = *(const int4*)(ka + 4096);
    vr0 = *(const int4*)(va);
    vr1 = *(const int4*)(va + 65536);

    const int NT = L_SEQ / KVB;   // 16
    u16* pw = &Ps[wid][0];
    const int pkey = lo << 3;
    for (int t = 0; t < NT; t++) {
        __syncthreads();
        *(int4*)(kdst)        = kr0;
        *(int4*)(kdst + 4096) = kr1;
        *(int4*)(vdst)        = vr0;
        *(int4*)(vdst + 4096) = vr1;
        __syncthreads();
        if (t + 1 < NT) {
            int kv0 = (t + 1) * KVB;
            const u16* kan = ka + (size_t)kv0 * 64;
            const u16* van = va + kv0;
            kr0 = *(const int4*)(kan);
            kr1 = *(const int4*)(kan + 4096);
            vr0 = *(const int4*)(van);
            vr1 = *(const int4*)(van + 65536);
        }
        f32x4 s[8];
#pragma unroll
        for (int nt = 0; nt < 8; nt++) {
            int kr_ = nt * 16 + lo;
            const u16* kp = &Kb[kr_ * 64];
            int key = (kr_ & 7) << 3;
            short8 kf0 = *(const short8*)(kp + ((hi * 8) ^ key));
            short8 kf1 = *(const short8*)(kp + ((32 + hi * 8) ^ key));
            __builtin_amdgcn_s_setprio(1);
            f32x4 z = (f32x4){0.f, 0.f, 0.f, 0.f};
            z = __builtin_amdgcn_mfma_f32_16x16x32_bf16(kf0, qa0, z, 0, 0, 0);
            s[nt] = __builtin_amdgcn_mfma_f32_16x16x32_bf16(kf1, qa1, s[nt] = z, 0, 0, 0);
            __builtin_amdgcn_s_setprio(0);
        }
        float t0 = fmaxf(fmaxf(s[0][0], s[0][1]), fmaxf(s[0][2], s[0][3]));
        float t1 = fmaxf(fmaxf(s[1][0], s[1][1]), fmaxf(s[1][2], s[1][3]));
        float t2 = fmaxf(fmaxf(s[2][0], s[2][1]), fmaxf(s[2][2], s[2][3]));
        float t3 = fmaxf(fmaxf(s[3][0], s[3][1]), fmaxf(s[3][2], s[3][3]));
        float t4 = fmaxf(fmaxf(s[4][0], s[4][1]), fmaxf(s[4][2], s[4][3]));
        float t5 = fmaxf(fmaxf(s[5][0], s[5][1]), fmaxf(s[5][2], s[5][3]));
        float t6 = fmaxf(fmaxf(s[6][0], s[6][1]), fmaxf(s[6][2], s[6][3]));
        float t7 = fmaxf(fmaxf(s[7][0], s[7][1]), fmaxf(s[7][2], s[7][3]));
        float pmax = fmaxf(fmaxf(fmaxf(t0, t1), fmaxf(t2, t3)),
                           fmaxf(fmaxf(t4, t5), fmaxf(t6, t7)));
        pmax = fmaxf(pmax, __shfl_xor(pmax, 16));
        pmax = fmaxf(pmax, __shfl_xor(pmax, 32));
        if (!__all(pmax - m_ <= 8.f)) {
            float mn = fmaxf(m_, pmax);
            float al = exp2f(m_ - mn);
            m_ = mn;
            ls *= al;
#pragma unroll
            for (int dt = 0; dt < 4; dt++) oacc[dt] *= al;
        }
        float rsA = 0.f, rsB = 0.f, rsC = 0.f, rsD = 0.f;
#pragma unroll
        for (int nt = 0; nt < 8; nt++) {
            float p0 = exp2f(s[nt][0] - m_);
            float p1 = exp2f(s[nt][1] - m_);
            float p2 = exp2f(s[nt][2] - m_);
            float p3 = exp2f(s[nt][3] - m_);
            s[nt][0] = p0; s[nt][1] = p1; s[nt][2] = p2; s[nt][3] = p3;
            rsA += p0; rsB += p1; rsC += p2; rsD += p3;
        }
        ls += (rsA + rsB) + (rsC + rsD);
#pragma unroll
        for (int nt = 0; nt < 8; nt++) {
            unsigned w0, w1;
            asm("v_cvt_pk_bf16_f32 %0, %1, %2" : "=v"(w0) : "v"(s[nt][0]), "v"(s[nt][1]));
            asm("v_cvt_pk_bf16_f32 %0, %1, %2" : "=v"(w1) : "v"(s[nt][2]), "v"(s[nt][3]));
            uint2 pk2; pk2.x = w0; pk2.y = w1;
            *(uint2*)(pw + lo * KVB + ((nt * 16 + hi * 4) ^ pkey)) = pk2;
        }
        short8 pa0 = *(const short8*)(pw + lo * KVB + ((0 * 32 + hi * 8) ^ pkey));
        short8 pa1 = *(const short8*)(pw + lo * KVB + ((1 * 32 + hi * 8) ^ pkey));
        short8 pa2 = *(const short8*)(pw + lo * KVB + ((2 * 32 + hi * 8) ^ pkey));
        short8 pa3 = *(const short8*)(pw + lo * KVB + ((3 * 32 + hi * 8) ^ pkey));
#pragma unroll
        for (int dt = 0; dt < 4; dt++) {
            int vr_ = dt * 16 + lo;
            const u16* vp = &Vb[vr_ * KVB];
            int vkey = (vr_ & 15) << 3;
            short8 vf0 = *(const short8*)(vp + ((0 * 32 + hi * 8) ^ vkey));
            short8 vf1 = *(const short8*)(vp + ((1 * 32 + hi * 8) ^ vkey));
            short8 vf2 = *(const short8*)(vp + ((2 * 32 + hi * 8) ^ vkey));
            short8 vf3 = *(const short8*)(vp + ((3 * 32 + hi * 8) ^ vkey));
            __builtin_amdgcn_s_setprio(1);
            oacc[dt] = __builtin_amdgcn_mfma_f32_16x16x32_bf16(vf0, pa0, oacc[dt], 0, 0, 0);
            oacc[dt] = __builtin_amdgcn_mfma_f32_16x16x32_bf16(vf1, pa1, oacc[dt], 0, 0, 0);
            oacc[dt] = __builtin_amdgcn_mfma_f32_16x16x32_bf16(vf2, pa2, oacc[dt], 0, 0, 0);
            oacc[dt] = __builtin_amdgcn_mfma_f32_16x16x32_bf16(vf3, pa3, oacc[dt], 0, 0, 0);
            __builtin_amdgcn_s_setprio(0);
        }
    }
    ls += __shfl_xor(ls, 16);
    ls += __shfl_xor(ls, 32);
    float inv = 1.f / ls;
    int qrow = q0 + lo;
    u16* orow = outp + ((size_t)(b * L_SEQ + qrow)) * 768 + h * 64;
#pragma unroll
    for (int dt = 0; dt < 4; dt++) {
        unsigned w0, w1;
        float o0 = oacc[dt][0] * inv, o1 = oacc[dt][1] * inv;
        float o2 = oacc[dt][2] * inv, o3 = oacc[dt][3] * inv;
        asm("v_cvt_pk_bf16_f32 %0, %1, %2" : "=v"(w0) : "v"(o0), "v"(o1));
        asm("v_cvt_pk_bf16_f32 %0, %1, %2" : "=v"(w1) : "v"(o2), "v"(o3));
        uint2 pk2; pk2.x = w0; pk2.y = w1;
        *(uint2*)(orow + dt * 16 + hi * 4) = pk2;
    }
}

extern "C" void kernel_launch(void* const* d_in, const int* in_sizes, int n_in,
                              void* d_out, int out_size, void* d_ws, size_t ws_size,
                              hipStream_t stream)
{
    const float* x      = (const float*)d_in[0];
    const float* c      = (const float*)d_in[1];
    const float* fcos   = (const float*)d_in[2];
    const float* fsin   = (const float*)d_in[3];
    const float* Wq     = (const float*)d_in[4];
    const float* Wk     = (const float*)d_in[5];
    const float* Wv     = (const float*)d_in[6];
    const float* Wo     = (const float*)d_in[7];
    const float* cw1    = (const float*)d_in[8];
    const float* cb1    = (const float*)d_in[9];
    const float* cw2    = (const float*)d_in[10];
    const float* cb2    = (const float*)d_in[11];
    const float* anw    = (const float*)d_in[12];
    const float* Walpha = (const float*)d_in[13];
    const float* Wbeta  = (const float*)d_in[14];
    const float* Wgamma = (const float*)d_in[15];
    const float* Wgate  = (const float*)d_in[16];
    const float* Whid   = (const float*)d_in[17];
    const float* Wout   = (const float*)d_in[18];
    const float* fnw    = (const float*)d_in[19];
    const float* Wbetaf = (const float*)d_in[20];
    const float* Wgammaf= (const float*)d_in[21];

    const int M = 4096; // B*L
    char* ws = (char*)d_ws;
    size_t off = 0;
    auto alloc = [&](size_t bytes) -> char* {
        char* p = ws + off;
        off += (bytes + 255) & ~(size_t)255;
        return p;
    };
    u16* wq_t   = (u16*)alloc((size_t)768 * 768 * 2);
    u16* wk_t   = (u16*)alloc((size_t)768 * 768 * 2);
    u16* wv_t   = (u16*)alloc((size_t)768 * 768 * 2);
    u16* wo_t   = (u16*)alloc((size_t)768 * 768 * 2);
    u16* gate_t = (u16*)alloc((size_t)3072 * 768 * 2);
    u16* hid_t  = (u16*)alloc((size_t)3072 * 768 * 2);
    u16* out_t  = (u16*)alloc((size_t)768 * 3072 * 2);
    float* part1 = (float*)alloc((size_t)8 * 2 * 3072 * 4);
    float* part2 = (float*)alloc((size_t)8 * 2 * 768 * 4);
    float* mods = (float*)alloc(5 * 2 * 768 * 4);
    u16* hbuf   = (u16*)alloc((size_t)M * 768 * 2);
    u16* qrope  = (u16*)alloc((size_t)M * 768 * 2);
    u16* krope  = (u16*)alloc((size_t)M * 768 * 2);
    u16* vtb    = (u16*)alloc((size_t)M * 768 * 2);
    u16* attnh  = (u16*)alloc((size_t)M * 768 * 2);
    u16* ybuf   = (u16*)alloc((size_t)M * 768 * 2);
    u16* ffbuf  = (u16*)alloc((size_t)M * 3072 * 2);

    // 1. ALL weight transposes in one launch
    transpose_all<<<9216, 256, 0, stream>>>(
        Wq, Wk, Wv, Wo, Wgate, Whid, Wout,
        wq_t, wk_t, wv_t, wo_t, gate_t, hid_t, out_t);

    // 2. conditioning path
    cond_mlp1<<<dim3(12, 8), 256, 0, stream>>>(c, cw1, part1);
    cond_mlp2<<<dim3(12, 8), 256, 0, stream>>>(part1, cb1, cw2, part2);
    mod_gemm<<<dim3(12, 5), 256, 0, stream>>>(
        part2, cb2, Wgamma, Wbeta, Walpha, Wgammaf, Wbetaf, mods);

    // 3. h = rms(x)*gamma_a + beta_a (fp32 input)
    rmsnorm_mod<0><<<M, 256, 0, stream>>>(x, anw, mods + 0 * 1536, mods + 1 * 1536, hbuf);

    // 4. fused QKV GEMM + RoPE + V-transpose epilogue
    gemm_qkv_rope<<<dim3(32, 18), 256, 0, stream>>>(
        hbuf, wq_t, fcos, fsin, qrope, krope, vtb, M, 2304, 768);

    // 5. attention -> attnh (B,L,D) bf16
    attn_fwd<<<dim3(384), 512, 0, stream>>>(qrope, krope, vtb, attnh);

    // 6. O-proj + residual: ybuf(bf16) = x + (attnh @ Wo) * alpha_a
    gemm_res64<0><<<dim3(64, 6), 256, 0, stream>>>(
        attnh, wo_t, ybuf, x, mods + 2 * 1536, M, 768, 768);

    // 7. h2 = rms(y)*gamma_f + beta_f (bf16 input)
    rmsnorm_mod<1><<<M, 256, 0, stream>>>(ybuf, fnw, mods + 3 * 1536, mods + 4 * 1536, hbuf);

    // 8. fused gate/hidden GEMM + silu-mul -> ffbuf
    gemm_ffn1<<<dim3(32, 48), 256, 0, stream>>>(
        hbuf, gate_t, hid_t, ffbuf, M, 3072, 768);

    // 9. out(fp32) = y(bf16) + (ff @ Wout) * gamma_f
    gemm_res64<1><<<dim3(64, 6), 256, 0, stream>>>(
        ffbuf, out_t, d_out, ybuf, mods + 3 * 1536, M, 768, 3072);
}

// Round 20
// 242.253 us; speedup vs baseline: 1.0820x; 1.0061x over previous
//
#include <hip/hip_runtime.h>

typedef unsigned short u16;
typedef __attribute__((ext_vector_type(8))) short short8;
typedef __attribute__((ext_vector_type(4))) float f32x4;

#define L_SEQ 2048
#define NHEAD 12
#define KVB 128
#define QBLK 128

__device__ __forceinline__ u16 f2bf(float f) {
    union { float f; unsigned u; } x; x.f = f;
    unsigned r = x.u + 0x7fffu + ((x.u >> 16) & 1u);
    return (u16)(r >> 16);
}
__device__ __forceinline__ float bf2f(u16 u) {
    union { unsigned u; float f; } x; x.u = ((unsigned)u) << 16;
    return x.f;
}
__device__ __forceinline__ float silu_f(float x) { return x / (1.f + __expf(-x)); }

// async global->LDS, 16B per lane. LDS dest must be wave-uniform base + lane*16.
__device__ __forceinline__ void gload16(const u16* g, u16* l) {
    __builtin_amdgcn_global_load_lds(
        (const __attribute__((address_space(1))) void*)g,
        (__attribute__((address_space(3))) void*)l, 16, 0, 0);
}

// ---------------- ALL weight transposes in one launch: W(K,N) -> Wt(N,K) -----------
__global__ __launch_bounds__(256) void transpose_all(
    const float* __restrict__ S0, const float* __restrict__ S1,
    const float* __restrict__ S2, const float* __restrict__ S3,
    const float* __restrict__ S4, const float* __restrict__ S5,
    const float* __restrict__ S6,
    u16* __restrict__ D0, u16* __restrict__ D1, u16* __restrict__ D2,
    u16* __restrict__ D3, u16* __restrict__ D4, u16* __restrict__ D5,
    u16* __restrict__ D6)
{
    int id = blockIdx.x;
    const float* W; u16* Wt; int K, N, local;
    if (id < 2304) {
        int sec = id / 576; local = id - sec * 576; K = 768; N = 768;
        W  = (sec == 0) ? S0 : (sec == 1) ? S1 : (sec == 2) ? S2 : S3;
        Wt = (sec == 0) ? D0 : (sec == 1) ? D1 : (sec == 2) ? D2 : D3;
    } else if (id < 6912) {
        int sec = (id - 2304) / 2304; local = (id - 2304) - sec * 2304; K = 768; N = 3072;
        W = sec ? S5 : S4; Wt = sec ? D5 : D4;
    } else {
        local = id - 6912; K = 3072; N = 768; W = S6; Wt = D6;
    }
    int nx = N >> 5;
    int n0 = (local % nx) * 32, k0 = (local / nx) * 32;
    __shared__ float t[32][33];
    int tx = threadIdx.x & 31, ty = threadIdx.x >> 5; // ty 0..7
#pragma unroll
    for (int i = 0; i < 4; i++)
        t[ty + 8 * i][tx] = W[(size_t)(k0 + ty + 8 * i) * N + n0 + tx];
    __syncthreads();
#pragma unroll
    for (int i = 0; i < 4; i++)
        Wt[(size_t)(n0 + ty + 8 * i) * K + k0 + tx] = f2bf(t[tx][ty + 8 * i]);
}

// ---------------- cond MLP layer 1, K-split ----------
__global__ __launch_bounds__(256) void cond_mlp1(
    const float* __restrict__ c, const float* __restrict__ w1, float* __restrict__ part)
{
    int j = blockIdx.x * 256 + threadIdx.x; // 0..3071
    int d0 = blockIdx.y * 96;
    float a0 = 0.f, a1 = 0.f;
    for (int d = d0; d < d0 + 96; ++d) {
        float w = w1[(size_t)d * 3072 + j];
        a0 += c[d] * w;
        a1 += c[768 + d] * w;
    }
    part[(size_t)(blockIdx.y * 2 + 0) * 3072 + j] = a0;
    part[(size_t)(blockIdx.y * 2 + 1) * 3072 + j] = a1;
}

// ---------------- cond MLP layer 2, K-split ----------
__global__ __launch_bounds__(256) void cond_mlp2(
    const float* __restrict__ part, const float* __restrict__ b1,
    const float* __restrict__ w2, float* __restrict__ c2part)
{
    __shared__ float hid[2][384];
    const int tid = threadIdx.x;
    const int d0 = blockIdx.y * 384;
    for (int i = tid; i < 768; i += 256) {
        int b = i / 384, dd = i - b * 384;
        float s = b1[d0 + dd];
#pragma unroll
        for (int p = 0; p < 8; p++) s += part[(size_t)(p * 2 + b) * 3072 + d0 + dd];
        hid[b][dd] = silu_f(s);
    }
    __syncthreads();
    int jj = tid & 63, kc = tid >> 6;
    int j = blockIdx.x * 64 + jj;
    float a0 = 0.f, a1 = 0.f;
    for (int dd = kc * 96; dd < kc * 96 + 96; ++dd) {
        float w = w2[(size_t)(d0 + dd) * 768 + j];
        a0 += hid[0][dd] * w;
        a1 += hid[1][dd] * w;
    }
    __shared__ float r0[256], r1[256];
    r0[tid] = a0; r1[tid] = a1;
    __syncthreads();
    if (kc == 0) {
        a0 = r0[jj] + r0[64 + jj] + r0[128 + jj] + r0[192 + jj];
        a1 = r1[jj] + r1[64 + jj] + r1[128 + jj] + r1[192 + jj];
        c2part[(size_t)(blockIdx.y * 2 + 0) * 768 + j] = a0;
        c2part[(size_t)(blockIdx.y * 2 + 1) * 768 + j] = a1;
    }
}

// ---------------- 5 modulation vectors ----------
__global__ __launch_bounds__(256) void mod_gemm(
    const float* __restrict__ c2part, const float* __restrict__ b2,
    const float* __restrict__ W0, const float* __restrict__ W1,
    const float* __restrict__ W2, const float* __restrict__ W3,
    const float* __restrict__ W4, float* __restrict__ out)
{
    __shared__ float c2s[2][768];
    const int tid = threadIdx.x;
    for (int i = tid; i < 1536; i += 256) {
        int b = i / 768, d = i - b * 768;
        float s = b2[d];
#pragma unroll
        for (int p = 0; p < 8; p++) s += c2part[(size_t)(p * 2 + b) * 768 + d];
        c2s[b][d] = s;
    }
    __syncthreads();
    int w = blockIdx.y;
    const float* W = (w == 0) ? W0 : (w == 1) ? W1 : (w == 2) ? W2 : (w == 3) ? W3 : W4;
    int jj = tid & 63, kc = tid >> 6; // 4 k-chunks of 192
    int j = blockIdx.x * 64 + jj;
    float a0 = 0.f, a1 = 0.f;
    for (int d = kc * 192; d < kc * 192 + 192; ++d) {
        float ww = W[(size_t)d * 768 + j];
        a0 += c2s[0][d] * ww;
        a1 += c2s[1][d] * ww;
    }
    __shared__ float r0[256], r1[256];
    r0[tid] = a0; r1[tid] = a1;
    __syncthreads();
    if (kc == 0) {
        a0 = r0[jj] + r0[64 + jj] + r0[128 + jj] + r0[192 + jj];
        a1 = r1[jj] + r1[64 + jj] + r1[128 + jj] + r1[192 + jj];
        out[(size_t)(w * 2 + 0) * 768 + j] = a0;
        out[(size_t)(w * 2 + 1) * 768 + j] = a1;
    }
}

// ---------------- fused RMSNorm * gamma_mod + beta_mod -> bf16 ----------
// IN==0: fp32 input; IN==1: bf16 input.
template<int IN>
__global__ __launch_bounds__(256) void rmsnorm_mod(
    const void* __restrict__ xin, const float* __restrict__ nw,
    const float* __restrict__ gamma, const float* __restrict__ beta,
    u16* __restrict__ hout)
{
    int row = blockIdx.x;      // 0..4095
    int b = row >> 11;         // L=2048
    int t = threadIdx.x;
    float v0, v1, v2;
    if (IN == 0) {
        const float* xr = (const float*)xin + (size_t)row * 768;
        v0 = xr[t]; v1 = xr[t + 256]; v2 = xr[t + 512];
    } else {
        const u16* xr = (const u16*)xin + (size_t)row * 768;
        v0 = bf2f(xr[t]); v1 = bf2f(xr[t + 256]); v2 = bf2f(xr[t + 512]);
    }
    float ss = v0 * v0 + v1 * v1 + v2 * v2;
#pragma unroll
    for (int m = 1; m < 64; m <<= 1) ss += __shfl_xor(ss, m);
    __shared__ float red[4];
    if ((t & 63) == 0) red[t >> 6] = ss;
    __syncthreads();
    float tot = red[0] + red[1] + red[2] + red[3];
    float rr = rsqrtf(tot * (1.f / 768.f) + 1e-6f);
    u16* ho = hout + (size_t)row * 768;
    const float* g = gamma + (size_t)b * 768;
    const float* be = beta + (size_t)b * 768;
#pragma unroll
    for (int i = 0; i < 3; i++) {
        int col = t + i * 256;
        float v = (i == 0) ? v0 : (i == 1) ? v1 : v2;
        ho[col] = f2bf(v * rr * nw[col] * g[col] + be[col]);
    }
}

// ===================== BK=64 swizzled-LDS GEMM family ==============================
// LDS tile rows are 64 u16 (128B); granule (16B) swizzle: LDS[r][g] holds source
// granule g^(r&7) (same involution staged and read -> bank-conflict-free).
// R19: s_setprio removed from GEMMs (T5 null/negative on lockstep structures, m190).
// R20: s_setprio removed from attn too (our attn is 8-wave lockstep = m190-class).

// ---------------- QKV GEMM + fused RoPE + V-transpose epilogue ---------------------
// Q cols [0,768): rope*QSCALE -> qo(B,H,L,64). K cols [768,1536): rope -> ko.
// V cols [1536,2304): directly transposed -> vt(B,H,64,L) via packed 8B stores.
__global__ __launch_bounds__(256) void gemm_qkv_rope(
    const u16* __restrict__ A, const u16* __restrict__ Bt,
    const float* __restrict__ fc, const float* __restrict__ fs,
    u16* __restrict__ qo, u16* __restrict__ ko, u16* __restrict__ vt,
    int M, int N, int K)
{
    const float QSCALE = 0.125f * 1.44269504f;
    __shared__ __align__(16) u16 As[2][128 * 64];
    __shared__ __align__(16) u16 Bs[2][128 * 64];
    const int tid = threadIdx.x;
    const int lane = tid & 63, wid = tid >> 6;
    const int lo = lane & 15, hi = lane >> 4;
    const int bm = blockIdx.x * 128, bn = blockIdx.y * 128;
    const int wrow = (wid >> 1) * 64, wcol = (wid & 1) * 64;

    f32x4 acc[4][4];
#pragma unroll
    for (int a = 0; a < 4; a++)
#pragma unroll
        for (int b = 0; b < 4; b++)
            acc[a][b] = (f32x4){0.f, 0.f, 0.f, 0.f};

    auto stage = [&](int buf, int k0) {
#pragma unroll
        for (int p = 0; p < 4; p++) {
            int ch = tid + p * 256;
            int r = ch >> 3, g = ch & 7;
            gload16(A + (size_t)(bm + r) * K + k0 + ((g ^ (r & 7)) * 8), &As[buf][ch * 8]);
        }
#pragma unroll
        for (int p = 0; p < 4; p++) {
            int ch = tid + p * 256;
            int r = ch >> 3, g = ch & 7;
            gload16(Bt + (size_t)(bn + r) * K + k0 + ((g ^ (r & 7)) * 8), &Bs[buf][ch * 8]);
        }
    };

    stage(0, 0);
    int cur = 0;
    const int NT = K >> 6;   // BK=64
    for (int t = 0; t < NT; t++) {
        __syncthreads();
        if (t + 1 < NT) stage(cur ^ 1, (t + 1) * 64);
        short8 af[4][2], bfr[4][2];
#pragma unroll
        for (int mi = 0; mi < 4; mi++) {
            int r = wrow + mi * 16 + lo;
#pragma unroll
            for (int h = 0; h < 2; h++)
                af[mi][h] = *(const short8*)(&As[cur][r * 64 + (((h * 4 + hi) ^ (r & 7)) * 8)]);
        }
#pragma unroll
        for (int nj = 0; nj < 4; nj++) {
            int r = wcol + nj * 16 + lo;
#pragma unroll
            for (int h = 0; h < 2; h++)
                bfr[nj][h] = *(const short8*)(&Bs[cur][r * 64 + (((h * 4 + hi) ^ (r & 7)) * 8)]);
        }
#pragma unroll
        for (int mi = 0; mi < 4; mi++)
#pragma unroll
            for (int nj = 0; nj < 4; nj++) {
                acc[mi][nj] = __builtin_amdgcn_mfma_f32_16x16x32_bf16(af[mi][0], bfr[nj][0], acc[mi][nj], 0, 0, 0);
                acc[mi][nj] = __builtin_amdgcn_mfma_f32_16x16x32_bf16(af[mi][1], bfr[nj][1], acc[mi][nj], 0, 0, 0);
            }
        cur ^= 1;
    }
    // epilogue: which = 0 Q / 1 K / 2 V (wave-uniform per block since 768 = 6*128)
    const int which = bn / 768;
    if (which == 2) {
        // V: write transposed. Lane holds 4 consecutive l (i=0..3) at fixed d.
#pragma unroll
        for (int mi = 0; mi < 4; mi++)
#pragma unroll
            for (int nj = 0; nj < 4; nj++) {
                int row0 = bm + wrow + mi * 16 + hi * 4;   // l base (mult of 4)
                int col = bn + wcol + nj * 16 + lo;
                int within = col - 1536;
                int h = within >> 6, d = within & 63;
                int l0 = row0 & (L_SEQ - 1), b = row0 >> 11;
                unsigned w0, w1;
                asm("v_cvt_pk_bf16_f32 %0, %1, %2" : "=v"(w0) : "v"(acc[mi][nj][0]), "v"(acc[mi][nj][1]));
                asm("v_cvt_pk_bf16_f32 %0, %1, %2" : "=v"(w1) : "v"(acc[mi][nj][2]), "v"(acc[mi][nj][3]));
                uint2 pk2; pk2.x = w0; pk2.y = w1;
                *(uint2*)(vt + (((size_t)(b * NHEAD + h)) * 64 + d) * L_SEQ + l0) = pk2;
            }
    } else {
#pragma unroll
        for (int mi = 0; mi < 4; mi++)
#pragma unroll
            for (int nj = 0; nj < 4; nj++)
#pragma unroll
                for (int i = 0; i < 4; i++) {
                    int row = bm + wrow + mi * 16 + hi * 4 + i;
                    int col = bn + wcol + nj * 16 + lo;
                    float v = acc[mi][nj][i];
                    int within = col - which * 768;
                    int h = within >> 6, d = within & 63;
                    int l = row & (L_SEQ - 1), b = row >> 11;
                    int dp = d >> 1;
                    float cc = fc[l * 32 + dp], sn = fs[l * 32 + dp];
                    float pv = __shfl_xor(v, 1);
                    float r_;
                    if ((lo & 1) == 0) r_ = v * cc - pv * sn;   // even d
                    else               r_ = pv * sn + v * cc;   // odd d
                    if (which == 0) r_ *= QSCALE;
                    u16* dst = (which == 0) ? qo : ko;
                    dst[(((size_t)(b * NHEAD + h)) * L_SEQ + l) * 64 + d] = f2bf(r_);
                }
    }
}

// ---------------- generic BK=64 GEMM, residual epilogue ----------------------------
// MODE 0: X fp32, out bf16  (O-proj -> ybuf bf16)
// MODE 1: X bf16, out fp32  (final -> d_out fp32)
template<int MODE>
__global__ __launch_bounds__(256) void gemm_res64(
    const u16* __restrict__ A, const u16* __restrict__ Bt,
    void* __restrict__ outp, const void* __restrict__ X, const float* __restrict__ coef,
    int M, int N, int K)
{
    __shared__ __align__(16) u16 As[2][64 * 64];
    __shared__ __align__(16) u16 Bs[2][128 * 64];
    const int tid = threadIdx.x;
    const int lane = tid & 63, wid = tid >> 6;
    const int lo = lane & 15, hi = lane >> 4;
    const int bm = blockIdx.x * 64, bn = blockIdx.y * 128;
    const int wrow = (wid >> 1) * 32, wcol = (wid & 1) * 64;

    f32x4 acc[2][4];
#pragma unroll
    for (int a = 0; a < 2; a++)
#pragma unroll
        for (int b = 0; b < 4; b++)
            acc[a][b] = (f32x4){0.f, 0.f, 0.f, 0.f};

    auto stage = [&](int buf, int k0) {
#pragma unroll
        for (int p = 0; p < 2; p++) {
            int ch = tid + p * 256;
            int r = ch >> 3, g = ch & 7;
            gload16(A + (size_t)(bm + r) * K + k0 + ((g ^ (r & 7)) * 8), &As[buf][ch * 8]);
        }
#pragma unroll
        for (int p = 0; p < 4; p++) {
            int ch = tid + p * 256;
            int r = ch >> 3, g = ch & 7;
            gload16(Bt + (size_t)(bn + r) * K + k0 + ((g ^ (r & 7)) * 8), &Bs[buf][ch * 8]);
        }
    };

    stage(0, 0);
    int cur = 0;
    const int NT = K >> 6;
    for (int t = 0; t < NT; t++) {
        __syncthreads();
        if (t + 1 < NT) stage(cur ^ 1, (t + 1) * 64);
        short8 af[2][2], bfr[4][2];
#pragma unroll
        for (int mi = 0; mi < 2; mi++) {
            int r = wrow + mi * 16 + lo;
#pragma unroll
            for (int h = 0; h < 2; h++)
                af[mi][h] = *(const short8*)(&As[cur][r * 64 + (((h * 4 + hi) ^ (r & 7)) * 8)]);
        }
#pragma unroll
        for (int nj = 0; nj < 4; nj++) {
            int r = wcol + nj * 16 + lo;
#pragma unroll
            for (int h = 0; h < 2; h++)
                bfr[nj][h] = *(const short8*)(&Bs[cur][r * 64 + (((h * 4 + hi) ^ (r & 7)) * 8)]);
        }
#pragma unroll
        for (int mi = 0; mi < 2; mi++)
#pragma unroll
            for (int nj = 0; nj < 4; nj++) {
                acc[mi][nj] = __builtin_amdgcn_mfma_f32_16x16x32_bf16(af[mi][0], bfr[nj][0], acc[mi][nj], 0, 0, 0);
                acc[mi][nj] = __builtin_amdgcn_mfma_f32_16x16x32_bf16(af[mi][1], bfr[nj][1], acc[mi][nj], 0, 0, 0);
            }
        cur ^= 1;
    }
#pragma unroll
    for (int mi = 0; mi < 2; mi++)
#pragma unroll
        for (int nj = 0; nj < 4; nj++)
#pragma unroll
            for (int i = 0; i < 4; i++) {
                int row = bm + wrow + mi * 16 + hi * 4 + i;
                int col = bn + wcol + nj * 16 + lo;
                size_t idx = (size_t)row * N + col;
                int b = row >> 11;
                float base = (MODE == 0) ? ((const float*)X)[idx]
                                         : bf2f(((const u16*)X)[idx]);
                float v = base + acc[mi][nj][i] * coef[(size_t)b * N + col];
                if (MODE == 0) ((u16*)outp)[idx] = f2bf(v);
                else           ((float*)outp)[idx] = v;
            }
}

// ---------------- fused FFN1, BK=64: ff = bf16(silu(A@G^T) * (A@H^T)) --------------
__global__ __launch_bounds__(256) void gemm_ffn1(
    const u16* __restrict__ A, const u16* __restrict__ Gt, const u16* __restrict__ Ht,
    u16* __restrict__ ff, int M, int N, int K)
{
    __shared__ __align__(16) u16 As[2][128 * 64];
    __shared__ __align__(16) u16 Gs[2][64 * 64];
    __shared__ __align__(16) u16 Hs[2][64 * 64];
    const int tid = threadIdx.x;
    const int lane = tid & 63, wid = tid >> 6;
    const int lo = lane & 15, hi = lane >> 4;
    const int bm = blockIdx.x * 128, bn = blockIdx.y * 64;
    const int wrow = (wid >> 1) * 64, wcol = (wid & 1) * 32;

    f32x4 ag[4][2], ah[4][2];
#pragma unroll
    for (int a = 0; a < 4; a++)
#pragma unroll
        for (int b = 0; b < 2; b++) {
            ag[a][b] = (f32x4){0.f, 0.f, 0.f, 0.f};
            ah[a][b] = (f32x4){0.f, 0.f, 0.f, 0.f};
        }

    auto stage = [&](int buf, int k0) {
#pragma unroll
        for (int p = 0; p < 4; p++) {
            int ch = tid + p * 256;
            int r = ch >> 3, g = ch & 7;
            gload16(A + (size_t)(bm + r) * K + k0 + ((g ^ (r & 7)) * 8), &As[buf][ch * 8]);
        }
#pragma unroll
        for (int p = 0; p < 2; p++) {
            int ch = tid + p * 256;
            int r = ch >> 3, g = ch & 7;
            gload16(Gt + (size_t)(bn + r) * K + k0 + ((g ^ (r & 7)) * 8), &Gs[buf][ch * 8]);
        }
#pragma unroll
        for (int p = 0; p < 2; p++) {
            int ch = tid + p * 256;
            int r = ch >> 3, g = ch & 7;
            gload16(Ht + (size_t)(bn + r) * K + k0 + ((g ^ (r & 7)) * 8), &Hs[buf][ch * 8]);
        }
    };

    stage(0, 0);
    int cur = 0;
    const int NT = K >> 6;
    for (int t = 0; t < NT; t++) {
        __syncthreads();
        if (t + 1 < NT) stage(cur ^ 1, (t + 1) * 64);
        short8 af[4][2], gf[2][2], hf[2][2];
#pragma unroll
        for (int mi = 0; mi < 4; mi++) {
            int r = wrow + mi * 16 + lo;
#pragma unroll
            for (int h = 0; h < 2; h++)
                af[mi][h] = *(const short8*)(&As[cur][r * 64 + (((h * 4 + hi) ^ (r & 7)) * 8)]);
        }
#pragma unroll
        for (int nj = 0; nj < 2; nj++) {
            int r = wcol + nj * 16 + lo;
#pragma unroll
            for (int h = 0; h < 2; h++) {
                gf[nj][h] = *(const short8*)(&Gs[cur][r * 64 + (((h * 4 + hi) ^ (r & 7)) * 8)]);
                hf[nj][h] = *(const short8*)(&Hs[cur][r * 64 + (((h * 4 + hi) ^ (r & 7)) * 8)]);
            }
        }
#pragma unroll
        for (int mi = 0; mi < 4; mi++)
#pragma unroll
            for (int nj = 0; nj < 2; nj++) {
                ag[mi][nj] = __builtin_amdgcn_mfma_f32_16x16x32_bf16(af[mi][0], gf[nj][0], ag[mi][nj], 0, 0, 0);
                ag[mi][nj] = __builtin_amdgcn_mfma_f32_16x16x32_bf16(af[mi][1], gf[nj][1], ag[mi][nj], 0, 0, 0);
                ah[mi][nj] = __builtin_amdgcn_mfma_f32_16x16x32_bf16(af[mi][0], hf[nj][0], ah[mi][nj], 0, 0, 0);
                ah[mi][nj] = __builtin_amdgcn_mfma_f32_16x16x32_bf16(af[mi][1], hf[nj][1], ah[mi][nj], 0, 0, 0);
            }
        cur ^= 1;
    }
#pragma unroll
    for (int mi = 0; mi < 4; mi++)
#pragma unroll
        for (int nj = 0; nj < 2; nj++)
#pragma unroll
            for (int i = 0; i < 4; i++) {
                int row = bm + wrow + mi * 16 + hi * 4 + i;
                int col = bn + wcol + nj * 16 + lo;
                ff[(size_t)row * N + col] = f2bf(silu_f(ag[mi][nj][i]) * ah[mi][nj][i]);
            }
}

// ---------------- flash attention: 512 threads (8 waves), QBLK=128, KVB=128 --------
// R20: setprio removed (this is an 8-wave lockstep structure = m190-class, not the
// independent-wave m191 structure where T5 was positive).
__global__ __launch_bounds__(512) void attn_fwd(
    const u16* __restrict__ q, const u16* __restrict__ k, const u16* __restrict__ vt,
    u16* __restrict__ outp)
{
    __shared__ __align__(16) u16 Kb[KVB * 64];      // 16 KB
    __shared__ __align__(16) u16 Vb[64 * KVB];      // 16 KB
    __shared__ __align__(16) u16 Ps[8][16 * KVB];   // 32 KB
    const int tid = threadIdx.x;
    const int lane = tid & 63, wid = tid >> 6;      // 8 waves
    const int lo = lane & 15, hi = lane >> 4;
    const int lid = blockIdx.x;
    const int xcd = lid & 7, li = lid >> 3;          // li 0..47
    const int bh = xcd * 3 + (li >> 4);              // 3 heads per XCD
    const int qt = li & 15;                          // 16 q-tiles of 128
    const int b = bh / NHEAD, h = bh % NHEAD;
    const int q0 = qt * QBLK + wid * 16;
    const u16* qb = q + ((size_t)bh * L_SEQ + q0) * 64;
    const u16* kbase = k + (size_t)bh * L_SEQ * 64;
    const u16* vbase = vt + (size_t)bh * 64 * L_SEQ;

    short8 qa0 = *(const short8*)(qb + lo * 64 + hi * 8);
    short8 qa1 = *(const short8*)(qb + lo * 64 + 32 + hi * 8);

    f32x4 oacc[4];
#pragma unroll
    for (int dt = 0; dt < 4; dt++) oacc[dt] = (f32x4){0.f, 0.f, 0.f, 0.f};
    float m_ = -1e30f, ls = 0.f;

    const int rk = tid >> 3, gk = tid & 7;
    const u16* ka = kbase + (size_t)rk * 64 + ((gk ^ (rk & 7)) * 8);
    const int rv = tid >> 4, gv = tid & 15;
    const u16* va = vbase + (size_t)rv * L_SEQ + ((gv ^ (rv & 15)) * 8);
    u16* kdst = &Kb[tid * 8];
    u16* vdst = &Vb[tid * 8];

    int4 kr0, kr1, vr0, vr1;
    kr0 = *(const int4*)(ka);
    kr1 = *(const int4*)(ka + 4096);
    vr0 = *(const int4*)(va);
    vr1 = *(const int4*)(va + 65536);

    const int NT = L_SEQ / KVB;   // 16
    u16* pw = &Ps[wid][0];
    const int pkey = lo << 3;
    for (int t = 0; t < NT; t++) {
        __syncthreads();
        *(int4*)(kdst)        = kr0;
        *(int4*)(kdst + 4096) = kr1;
        *(int4*)(vdst)        = vr0;
        *(int4*)(vdst + 4096) = vr1;
        __syncthreads();
        if (t + 1 < NT) {
            int kv0 = (t + 1) * KVB;
            const u16* kan = ka + (size_t)kv0 * 64;
            const u16* van = va + kv0;
            kr0 = *(const int4*)(kan);
            kr1 = *(const int4*)(kan + 4096);
            vr0 = *(const int4*)(van);
            vr1 = *(const int4*)(van + 65536);
        }
        f32x4 s[8];
#pragma unroll
        for (int nt = 0; nt < 8; nt++) {
            int kr_ = nt * 16 + lo;
            const u16* kp = &Kb[kr_ * 64];
            int key = (kr_ & 7) << 3;
            short8 kf0 = *(const short8*)(kp + ((hi * 8) ^ key));
            short8 kf1 = *(const short8*)(kp + ((32 + hi * 8) ^ key));
            f32x4 z = (f32x4){0.f, 0.f, 0.f, 0.f};
            z = __builtin_amdgcn_mfma_f32_16x16x32_bf16(kf0, qa0, z, 0, 0, 0);
            s[nt] = __builtin_amdgcn_mfma_f32_16x16x32_bf16(kf1, qa1, s[nt] = z, 0, 0, 0);
        }
        float t0 = fmaxf(fmaxf(s[0][0], s[0][1]), fmaxf(s[0][2], s[0][3]));
        float t1 = fmaxf(fmaxf(s[1][0], s[1][1]), fmaxf(s[1][2], s[1][3]));
        float t2 = fmaxf(fmaxf(s[2][0], s[2][1]), fmaxf(s[2][2], s[2][3]));
        float t3 = fmaxf(fmaxf(s[3][0], s[3][1]), fmaxf(s[3][2], s[3][3]));
        float t4 = fmaxf(fmaxf(s[4][0], s[4][1]), fmaxf(s[4][2], s[4][3]));
        float t5 = fmaxf(fmaxf(s[5][0], s[5][1]), fmaxf(s[5][2], s[5][3]));
        float t6 = fmaxf(fmaxf(s[6][0], s[6][1]), fmaxf(s[6][2], s[6][3]));
        float t7 = fmaxf(fmaxf(s[7][0], s[7][1]), fmaxf(s[7][2], s[7][3]));
        float pmax = fmaxf(fmaxf(fmaxf(t0, t1), fmaxf(t2, t3)),
                           fmaxf(fmaxf(t4, t5), fmaxf(t6, t7)));
        pmax = fmaxf(pmax, __shfl_xor(pmax, 16));
        pmax = fmaxf(pmax, __shfl_xor(pmax, 32));
        if (!__all(pmax - m_ <= 8.f)) {
            float mn = fmaxf(m_, pmax);
            float al = exp2f(m_ - mn);
            m_ = mn;
            ls *= al;
#pragma unroll
            for (int dt = 0; dt < 4; dt++) oacc[dt] *= al;
        }
        float rsA = 0.f, rsB = 0.f, rsC = 0.f, rsD = 0.f;
#pragma unroll
        for (int nt = 0; nt < 8; nt++) {
            float p0 = exp2f(s[nt][0] - m_);
            float p1 = exp2f(s[nt][1] - m_);
            float p2 = exp2f(s[nt][2] - m_);
            float p3 = exp2f(s[nt][3] - m_);
            s[nt][0] = p0; s[nt][1] = p1; s[nt][2] = p2; s[nt][3] = p3;
            rsA += p0; rsB += p1; rsC += p2; rsD += p3;
        }
        ls += (rsA + rsB) + (rsC + rsD);
#pragma unroll
        for (int nt = 0; nt < 8; nt++) {
            unsigned w0, w1;
            asm("v_cvt_pk_bf16_f32 %0, %1, %2" : "=v"(w0) : "v"(s[nt][0]), "v"(s[nt][1]));
            asm("v_cvt_pk_bf16_f32 %0, %1, %2" : "=v"(w1) : "v"(s[nt][2]), "v"(s[nt][3]));
            uint2 pk2; pk2.x = w0; pk2.y = w1;
            *(uint2*)(pw + lo * KVB + ((nt * 16 + hi * 4) ^ pkey)) = pk2;
        }
        short8 pa0 = *(const short8*)(pw + lo * KVB + ((0 * 32 + hi * 8) ^ pkey));
        short8 pa1 = *(const short8*)(pw + lo * KVB + ((1 * 32 + hi * 8) ^ pkey));
        short8 pa2 = *(const short8*)(pw + lo * KVB + ((2 * 32 + hi * 8) ^ pkey));
        short8 pa3 = *(const short8*)(pw + lo * KVB + ((3 * 32 + hi * 8) ^ pkey));
#pragma unroll
        for (int dt = 0; dt < 4; dt++) {
            int vr_ = dt * 16 + lo;
            const u16* vp = &Vb[vr_ * KVB];
            int vkey = (vr_ & 15) << 3;
            short8 vf0 = *(const short8*)(vp + ((0 * 32 + hi * 8) ^ vkey));
            short8 vf1 = *(const short8*)(vp + ((1 * 32 + hi * 8) ^ vkey));
            short8 vf2 = *(const short8*)(vp + ((2 * 32 + hi * 8) ^ vkey));
            short8 vf3 = *(const short8*)(vp + ((3 * 32 + hi * 8) ^ vkey));
            oacc[dt] = __builtin_amdgcn_mfma_f32_16x16x32_bf16(vf0, pa0, oacc[dt], 0, 0, 0);
            oacc[dt] = __builtin_amdgcn_mfma_f32_16x16x32_bf16(vf1, pa1, oacc[dt], 0, 0, 0);
            oacc[dt] = __builtin_amdgcn_mfma_f32_16x16x32_bf16(vf2, pa2, oacc[dt], 0, 0, 0);
            oacc[dt] = __builtin_amdgcn_mfma_f32_16x16x32_bf16(vf3, pa3, oacc[dt], 0, 0, 0);
        }
    }
    ls += __shfl_xor(ls, 16);
    ls += __shfl_xor(ls, 32);
    float inv = 1.f / ls;
    int qrow = q0 + lo;
    u16* orow = outp + ((size_t)(b * L_SEQ + qrow)) * 768 + h * 64;
#pragma unroll
    for (int dt = 0; dt < 4; dt++) {
        unsigned w0, w1;
        float o0 = oacc[dt][0] * inv, o1 = oacc[dt][1] * inv;
        float o2 = oacc[dt][2] * inv, o3 = oacc[dt][3] * inv;
        asm("v_cvt_pk_bf16_f32 %0, %1, %2" : "=v"(w0) : "v"(o0), "v"(o1));
        asm("v_cvt_pk_bf16_f32 %0, %1, %2" : "=v"(w1) : "v"(o2), "v"(o3));
        uint2 pk2; pk2.x = w0; pk2.y = w1;
        *(uint2*)(orow + dt * 16 + hi * 4) = pk2;
    }
}

extern "C" void kernel_launch(void* const* d_in, const int* in_sizes, int n_in,
                              void* d_out, int out_size, void* d_ws, size_t ws_size,
                              hipStream_t stream)
{
    const float* x      = (const float*)d_in[0];
    const float* c      = (const float*)d_in[1];
    const float* fcos   = (const float*)d_in[2];
    const float* fsin   = (const float*)d_in[3];
    const float* Wq     = (const float*)d_in[4];
    const float* Wk     = (const float*)d_in[5];
    const float* Wv     = (const float*)d_in[6];
    const float* Wo     = (const float*)d_in[7];
    const float* cw1    = (const float*)d_in[8];
    const float* cb1    = (const float*)d_in[9];
    const float* cw2    = (const float*)d_in[10];
    const float* cb2    = (const float*)d_in[11];
    const float* anw    = (const float*)d_in[12];
    const float* Walpha = (const float*)d_in[13];
    const float* Wbeta  = (const float*)d_in[14];
    const float* Wgamma = (const float*)d_in[15];
    const float* Wgate  = (const float*)d_in[16];
    const float* Whid   = (const float*)d_in[17];
    const float* Wout   = (const float*)d_in[18];
    const float* fnw    = (const float*)d_in[19];
    const float* Wbetaf = (const float*)d_in[20];
    const float* Wgammaf= (const float*)d_in[21];

    const int M = 4096; // B*L
    char* ws = (char*)d_ws;
    size_t off = 0;
    auto alloc = [&](size_t bytes) -> char* {
        char* p = ws + off;
        off += (bytes + 255) & ~(size_t)255;
        return p;
    };
    u16* wq_t   = (u16*)alloc((size_t)768 * 768 * 2);
    u16* wk_t   = (u16*)alloc((size_t)768 * 768 * 2);
    u16* wv_t   = (u16*)alloc((size_t)768 * 768 * 2);
    u16* wo_t   = (u16*)alloc((size_t)768 * 768 * 2);
    u16* gate_t = (u16*)alloc((size_t)3072 * 768 * 2);
    u16* hid_t  = (u16*)alloc((size_t)3072 * 768 * 2);
    u16* out_t  = (u16*)alloc((size_t)768 * 3072 * 2);
    float* part1 = (float*)alloc((size_t)8 * 2 * 3072 * 4);
    float* part2 = (float*)alloc((size_t)8 * 2 * 768 * 4);
    float* mods = (float*)alloc(5 * 2 * 768 * 4);
    u16* hbuf   = (u16*)alloc((size_t)M * 768 * 2);
    u16* qrope  = (u16*)alloc((size_t)M * 768 * 2);
    u16* krope  = (u16*)alloc((size_t)M * 768 * 2);
    u16* vtb    = (u16*)alloc((size_t)M * 768 * 2);
    u16* attnh  = (u16*)alloc((size_t)M * 768 * 2);
    u16* ybuf   = (u16*)alloc((size_t)M * 768 * 2);
    u16* ffbuf  = (u16*)alloc((size_t)M * 3072 * 2);

    // 1. ALL weight transposes in one launch
    transpose_all<<<9216, 256, 0, stream>>>(
        Wq, Wk, Wv, Wo, Wgate, Whid, Wout,
        wq_t, wk_t, wv_t, wo_t, gate_t, hid_t, out_t);

    // 2. conditioning path
    cond_mlp1<<<dim3(12, 8), 256, 0, stream>>>(c, cw1, part1);
    cond_mlp2<<<dim3(12, 8), 256, 0, stream>>>(part1, cb1, cw2, part2);
    mod_gemm<<<dim3(12, 5), 256, 0, stream>>>(
        part2, cb2, Wgamma, Wbeta, Walpha, Wgammaf, Wbetaf, mods);

    // 3. h = rms(x)*gamma_a + beta_a (fp32 input)
    rmsnorm_mod<0><<<M, 256, 0, stream>>>(x, anw, mods + 0 * 1536, mods + 1 * 1536, hbuf);

    // 4. fused QKV GEMM + RoPE + V-transpose epilogue
    gemm_qkv_rope<<<dim3(32, 18), 256, 0, stream>>>(
        hbuf, wq_t, fcos, fsin, qrope, krope, vtb, M, 2304, 768);

    // 5. attention -> attnh (B,L,D) bf16
    attn_fwd<<<dim3(384), 512, 0, stream>>>(qrope, krope, vtb, attnh);

    // 6. O-proj + residual: ybuf(bf16) = x + (attnh @ Wo) * alpha_a
    gemm_res64<0><<<dim3(64, 6), 256, 0, stream>>>(
        attnh, wo_t, ybuf, x, mods + 2 * 1536, M, 768, 768);

    // 7. h2 = rms(y)*gamma_f + beta_f (bf16 input)
    rmsnorm_mod<1><<<M, 256, 0, stream>>>(ybuf, fnw, mods + 3 * 1536, mods + 4 * 1536, hbuf);

    // 8. fused gate/hidden GEMM + silu-mul -> ffbuf
    gemm_ffn1<<<dim3(32, 48), 256, 0, stream>>>(
        hbuf, gate_t, hid_t, ffbuf, M, 3072, 768);

    // 9. out(fp32) = y(bf16) + (ff @ Wout) * gamma_f
    gemm_res64<1><<<dim3(64, 6), 256, 0, stream>>>(
        ffbuf, out_t, d_out, ybuf, mods + 3 * 1536, M, 768, 3072);
}

// Round 21
// 241.146 us; speedup vs baseline: 1.0869x; 1.0046x over previous
//
#include <hip/hip_runtime.h>

typedef unsigned short u16;
typedef __attribute__((ext_vector_type(8))) short short8;
typedef __attribute__((ext_vector_type(4))) float f32x4;

#define L_SEQ 2048
#define NHEAD 12
#define KVB 128
#define QBLK 128

__device__ __forceinline__ u16 f2bf(float f) {
    union { float f; unsigned u; } x; x.f = f;
    unsigned r = x.u + 0x7fffu + ((x.u >> 16) & 1u);
    return (u16)(r >> 16);
}
__device__ __forceinline__ float bf2f(u16 u) {
    union { unsigned u; float f; } x; x.u = ((unsigned)u) << 16;
    return x.f;
}
__device__ __forceinline__ float silu_f(float x) { return x / (1.f + __expf(-x)); }

// async global->LDS, 16B per lane. LDS dest must be wave-uniform base + lane*16.
__device__ __forceinline__ void gload16(const u16* g, u16* l) {
    __builtin_amdgcn_global_load_lds(
        (const __attribute__((address_space(1))) void*)g,
        (__attribute__((address_space(3))) void*)l, 16, 0, 0);
}

// ---------------- ALL weight transposes in one launch: W(K,N) -> Wt(N,K) -----------
__global__ __launch_bounds__(256) void transpose_all(
    const float* __restrict__ S0, const float* __restrict__ S1,
    const float* __restrict__ S2, const float* __restrict__ S3,
    const float* __restrict__ S4, const float* __restrict__ S5,
    const float* __restrict__ S6,
    u16* __restrict__ D0, u16* __restrict__ D1, u16* __restrict__ D2,
    u16* __restrict__ D3, u16* __restrict__ D4, u16* __restrict__ D5,
    u16* __restrict__ D6)
{
    int id = blockIdx.x;
    const float* W; u16* Wt; int K, N, local;
    if (id < 2304) {
        int sec = id / 576; local = id - sec * 576; K = 768; N = 768;
        W  = (sec == 0) ? S0 : (sec == 1) ? S1 : (sec == 2) ? S2 : S3;
        Wt = (sec == 0) ? D0 : (sec == 1) ? D1 : (sec == 2) ? D2 : D3;
    } else if (id < 6912) {
        int sec = (id - 2304) / 2304; local = (id - 2304) - sec * 2304; K = 768; N = 3072;
        W = sec ? S5 : S4; Wt = sec ? D5 : D4;
    } else {
        local = id - 6912; K = 3072; N = 768; W = S6; Wt = D6;
    }
    int nx = N >> 5;
    int n0 = (local % nx) * 32, k0 = (local / nx) * 32;
    __shared__ float t[32][33];
    int tx = threadIdx.x & 31, ty = threadIdx.x >> 5; // ty 0..7
#pragma unroll
    for (int i = 0; i < 4; i++)
        t[ty + 8 * i][tx] = W[(size_t)(k0 + ty + 8 * i) * N + n0 + tx];
    __syncthreads();
#pragma unroll
    for (int i = 0; i < 4; i++)
        Wt[(size_t)(n0 + ty + 8 * i) * K + k0 + tx] = f2bf(t[tx][ty + 8 * i]);
}

// ---------------- cond MLP layer 1, K-split ----------
__global__ __launch_bounds__(256) void cond_mlp1(
    const float* __restrict__ c, const float* __restrict__ w1, float* __restrict__ part)
{
    int j = blockIdx.x * 256 + threadIdx.x; // 0..3071
    int d0 = blockIdx.y * 96;
    float a0 = 0.f, a1 = 0.f;
    for (int d = d0; d < d0 + 96; ++d) {
        float w = w1[(size_t)d * 3072 + j];
        a0 += c[d] * w;
        a1 += c[768 + d] * w;
    }
    part[(size_t)(blockIdx.y * 2 + 0) * 3072 + j] = a0;
    part[(size_t)(blockIdx.y * 2 + 1) * 3072 + j] = a1;
}

// ---------------- cond MLP layer 2, K-split ----------
__global__ __launch_bounds__(256) void cond_mlp2(
    const float* __restrict__ part, const float* __restrict__ b1,
    const float* __restrict__ w2, float* __restrict__ c2part)
{
    __shared__ float hid[2][384];
    const int tid = threadIdx.x;
    const int d0 = blockIdx.y * 384;
    for (int i = tid; i < 768; i += 256) {
        int b = i / 384, dd = i - b * 384;
        float s = b1[d0 + dd];
#pragma unroll
        for (int p = 0; p < 8; p++) s += part[(size_t)(p * 2 + b) * 3072 + d0 + dd];
        hid[b][dd] = silu_f(s);
    }
    __syncthreads();
    int jj = tid & 63, kc = tid >> 6;
    int j = blockIdx.x * 64 + jj;
    float a0 = 0.f, a1 = 0.f;
    for (int dd = kc * 96; dd < kc * 96 + 96; ++dd) {
        float w = w2[(size_t)(d0 + dd) * 768 + j];
        a0 += hid[0][dd] * w;
        a1 += hid[1][dd] * w;
    }
    __shared__ float r0[256], r1[256];
    r0[tid] = a0; r1[tid] = a1;
    __syncthreads();
    if (kc == 0) {
        a0 = r0[jj] + r0[64 + jj] + r0[128 + jj] + r0[192 + jj];
        a1 = r1[jj] + r1[64 + jj] + r1[128 + jj] + r1[192 + jj];
        c2part[(size_t)(blockIdx.y * 2 + 0) * 768 + j] = a0;
        c2part[(size_t)(blockIdx.y * 2 + 1) * 768 + j] = a1;
    }
}

// ---------------- 5 modulation vectors ----------
__global__ __launch_bounds__(256) void mod_gemm(
    const float* __restrict__ c2part, const float* __restrict__ b2,
    const float* __restrict__ W0, const float* __restrict__ W1,
    const float* __restrict__ W2, const float* __restrict__ W3,
    const float* __restrict__ W4, float* __restrict__ out)
{
    __shared__ float c2s[2][768];
    const int tid = threadIdx.x;
    for (int i = tid; i < 1536; i += 256) {
        int b = i / 768, d = i - b * 768;
        float s = b2[d];
#pragma unroll
        for (int p = 0; p < 8; p++) s += c2part[(size_t)(p * 2 + b) * 768 + d];
        c2s[b][d] = s;
    }
    __syncthreads();
    int w = blockIdx.y;
    const float* W = (w == 0) ? W0 : (w == 1) ? W1 : (w == 2) ? W2 : (w == 3) ? W3 : W4;
    int jj = tid & 63, kc = tid >> 6; // 4 k-chunks of 192
    int j = blockIdx.x * 64 + jj;
    float a0 = 0.f, a1 = 0.f;
    for (int d = kc * 192; d < kc * 192 + 192; ++d) {
        float ww = W[(size_t)d * 768 + j];
        a0 += c2s[0][d] * ww;
        a1 += c2s[1][d] * ww;
    }
    __shared__ float r0[256], r1[256];
    r0[tid] = a0; r1[tid] = a1;
    __syncthreads();
    if (kc == 0) {
        a0 = r0[jj] + r0[64 + jj] + r0[128 + jj] + r0[192 + jj];
        a1 = r1[jj] + r1[64 + jj] + r1[128 + jj] + r1[192 + jj];
        out[(size_t)(w * 2 + 0) * 768 + j] = a0;
        out[(size_t)(w * 2 + 1) * 768 + j] = a1;
    }
}

// ---------------- fused RMSNorm * gamma_mod + beta_mod -> bf16, wave-per-row -------
// IN==0: fp32 input; IN==1: bf16 input. 4 waves/block = 4 rows/block, grid 1024.
// Lane owns 12 contiguous elements: vector loads (3x float4 / 3x 8B), wave shfl
// reduce (no LDS/barrier), packed cvt_pk stores (3x 8B).
template<int IN>
__global__ __launch_bounds__(256) void rmsnorm_mod(
    const void* __restrict__ xin, const float* __restrict__ nw,
    const float* __restrict__ gamma, const float* __restrict__ beta,
    u16* __restrict__ hout)
{
    const int tid = threadIdx.x;
    const int wid = tid >> 6, lane = tid & 63;
    const int row = blockIdx.x * 4 + wid;   // 0..4095
    const int b = row >> 11;                // L=2048
    const int col0 = lane * 12;

    float v[12];
    if (IN == 0) {
        const float* xr = (const float*)xin + (size_t)row * 768 + col0;
        float4 x0 = *(const float4*)(xr);
        float4 x1 = *(const float4*)(xr + 4);
        float4 x2 = *(const float4*)(xr + 8);
        v[0] = x0.x; v[1] = x0.y; v[2] = x0.z; v[3] = x0.w;
        v[4] = x1.x; v[5] = x1.y; v[6] = x1.z; v[7] = x1.w;
        v[8] = x2.x; v[9] = x2.y; v[10] = x2.z; v[11] = x2.w;
    } else {
        const u16* xr = (const u16*)xin + (size_t)row * 768 + col0;
        union { uint2 q; u16 s[4]; } u0, u1, u2;
        u0.q = *(const uint2*)(xr);
        u1.q = *(const uint2*)(xr + 4);
        u2.q = *(const uint2*)(xr + 8);
#pragma unroll
        for (int e = 0; e < 4; e++) {
            v[e]     = bf2f(u0.s[e]);
            v[4 + e] = bf2f(u1.s[e]);
            v[8 + e] = bf2f(u2.s[e]);
        }
    }
    // per-lane sum of squares (tree), then wave reduce
    float sA = v[0] * v[0] + v[1] * v[1];
    float sB = v[2] * v[2] + v[3] * v[3];
    float sC = v[4] * v[4] + v[5] * v[5];
    float sD = v[6] * v[6] + v[7] * v[7];
    float sE = v[8] * v[8] + v[9] * v[9];
    float sF = v[10] * v[10] + v[11] * v[11];
    float ss = ((sA + sB) + (sC + sD)) + (sE + sF);
#pragma unroll
    for (int m = 1; m < 64; m <<= 1) ss += __shfl_xor(ss, m);
    float rr = rsqrtf(ss * (1.f / 768.f) + 1e-6f);

    const float* nwp = nw + col0;
    const float* gp  = gamma + (size_t)b * 768 + col0;
    const float* bp  = beta + (size_t)b * 768 + col0;
    float o[12];
#pragma unroll
    for (int c4 = 0; c4 < 3; c4++) {
        float4 wv = *(const float4*)(nwp + c4 * 4);
        float4 gv = *(const float4*)(gp + c4 * 4);
        float4 bv = *(const float4*)(bp + c4 * 4);
        o[c4 * 4 + 0] = v[c4 * 4 + 0] * rr * wv.x * gv.x + bv.x;
        o[c4 * 4 + 1] = v[c4 * 4 + 1] * rr * wv.y * gv.y + bv.y;
        o[c4 * 4 + 2] = v[c4 * 4 + 2] * rr * wv.z * gv.z + bv.z;
        o[c4 * 4 + 3] = v[c4 * 4 + 3] * rr * wv.w * gv.w + bv.w;
    }
    u16* ho = hout + (size_t)row * 768 + col0;
#pragma unroll
    for (int c4 = 0; c4 < 3; c4++) {
        unsigned w0, w1;
        asm("v_cvt_pk_bf16_f32 %0, %1, %2" : "=v"(w0) : "v"(o[c4 * 4 + 0]), "v"(o[c4 * 4 + 1]));
        asm("v_cvt_pk_bf16_f32 %0, %1, %2" : "=v"(w1) : "v"(o[c4 * 4 + 2]), "v"(o[c4 * 4 + 3]));
        uint2 pk2; pk2.x = w0; pk2.y = w1;
        *(uint2*)(ho + c4 * 4) = pk2;
    }
}

// ===================== BK=64 swizzled-LDS GEMM family ==============================
// LDS tile rows are 64 u16 (128B); granule (16B) swizzle: LDS[r][g] holds source
// granule g^(r&7) (same involution staged and read -> bank-conflict-free).
// R19/R20: s_setprio removed everywhere (T5 null/negative on lockstep structures).

// ---------------- QKV GEMM + fused RoPE + V-transpose epilogue ---------------------
// Q cols [0,768): rope*QSCALE -> qo(B,H,L,64). K cols [768,1536): rope -> ko.
// V cols [1536,2304): directly transposed -> vt(B,H,64,L) via packed 8B stores.
__global__ __launch_bounds__(256) void gemm_qkv_rope(
    const u16* __restrict__ A, const u16* __restrict__ Bt,
    const float* __restrict__ fc, const float* __restrict__ fs,
    u16* __restrict__ qo, u16* __restrict__ ko, u16* __restrict__ vt,
    int M, int N, int K)
{
    const float QSCALE = 0.125f * 1.44269504f;
    __shared__ __align__(16) u16 As[2][128 * 64];
    __shared__ __align__(16) u16 Bs[2][128 * 64];
    const int tid = threadIdx.x;
    const int lane = tid & 63, wid = tid >> 6;
    const int lo = lane & 15, hi = lane >> 4;
    const int bm = blockIdx.x * 128, bn = blockIdx.y * 128;
    const int wrow = (wid >> 1) * 64, wcol = (wid & 1) * 64;

    f32x4 acc[4][4];
#pragma unroll
    for (int a = 0; a < 4; a++)
#pragma unroll
        for (int b = 0; b < 4; b++)
            acc[a][b] = (f32x4){0.f, 0.f, 0.f, 0.f};

    auto stage = [&](int buf, int k0) {
#pragma unroll
        for (int p = 0; p < 4; p++) {
            int ch = tid + p * 256;
            int r = ch >> 3, g = ch & 7;
            gload16(A + (size_t)(bm + r) * K + k0 + ((g ^ (r & 7)) * 8), &As[buf][ch * 8]);
        }
#pragma unroll
        for (int p = 0; p < 4; p++) {
            int ch = tid + p * 256;
            int r = ch >> 3, g = ch & 7;
            gload16(Bt + (size_t)(bn + r) * K + k0 + ((g ^ (r & 7)) * 8), &Bs[buf][ch * 8]);
        }
    };

    stage(0, 0);
    int cur = 0;
    const int NT = K >> 6;   // BK=64
    for (int t = 0; t < NT; t++) {
        __syncthreads();
        if (t + 1 < NT) stage(cur ^ 1, (t + 1) * 64);
        short8 af[4][2], bfr[4][2];
#pragma unroll
        for (int mi = 0; mi < 4; mi++) {
            int r = wrow + mi * 16 + lo;
#pragma unroll
            for (int h = 0; h < 2; h++)
                af[mi][h] = *(const short8*)(&As[cur][r * 64 + (((h * 4 + hi) ^ (r & 7)) * 8)]);
        }
#pragma unroll
        for (int nj = 0; nj < 4; nj++) {
            int r = wcol + nj * 16 + lo;
#pragma unroll
            for (int h = 0; h < 2; h++)
                bfr[nj][h] = *(const short8*)(&Bs[cur][r * 64 + (((h * 4 + hi) ^ (r & 7)) * 8)]);
        }
#pragma unroll
        for (int mi = 0; mi < 4; mi++)
#pragma unroll
            for (int nj = 0; nj < 4; nj++) {
                acc[mi][nj] = __builtin_amdgcn_mfma_f32_16x16x32_bf16(af[mi][0], bfr[nj][0], acc[mi][nj], 0, 0, 0);
                acc[mi][nj] = __builtin_amdgcn_mfma_f32_16x16x32_bf16(af[mi][1], bfr[nj][1], acc[mi][nj], 0, 0, 0);
            }
        cur ^= 1;
    }
    // epilogue: which = 0 Q / 1 K / 2 V (wave-uniform per block since 768 = 6*128)
    const int which = bn / 768;
    if (which == 2) {
        // V: write transposed. Lane holds 4 consecutive l (i=0..3) at fixed d.
#pragma unroll
        for (int mi = 0; mi < 4; mi++)
#pragma unroll
            for (int nj = 0; nj < 4; nj++) {
                int row0 = bm + wrow + mi * 16 + hi * 4;   // l base (mult of 4)
                int col = bn + wcol + nj * 16 + lo;
                int within = col - 1536;
                int h = within >> 6, d = within & 63;
                int l0 = row0 & (L_SEQ - 1), b = row0 >> 11;
                unsigned w0, w1;
                asm("v_cvt_pk_bf16_f32 %0, %1, %2" : "=v"(w0) : "v"(acc[mi][nj][0]), "v"(acc[mi][nj][1]));
                asm("v_cvt_pk_bf16_f32 %0, %1, %2" : "=v"(w1) : "v"(acc[mi][nj][2]), "v"(acc[mi][nj][3]));
                uint2 pk2; pk2.x = w0; pk2.y = w1;
                *(uint2*)(vt + (((size_t)(b * NHEAD + h)) * 64 + d) * L_SEQ + l0) = pk2;
            }
    } else {
#pragma unroll
        for (int mi = 0; mi < 4; mi++)
#pragma unroll
            for (int nj = 0; nj < 4; nj++)
#pragma unroll
                for (int i = 0; i < 4; i++) {
                    int row = bm + wrow + mi * 16 + hi * 4 + i;
                    int col = bn + wcol + nj * 16 + lo;
                    float v = acc[mi][nj][i];
                    int within = col - which * 768;
                    int h = within >> 6, d = within & 63;
                    int l = row & (L_SEQ - 1), b = row >> 11;
                    int dp = d >> 1;
                    float cc = fc[l * 32 + dp], sn = fs[l * 32 + dp];
                    float pv = __shfl_xor(v, 1);
                    float r_;
                    if ((lo & 1) == 0) r_ = v * cc - pv * sn;   // even d
                    else               r_ = pv * sn + v * cc;   // odd d
                    if (which == 0) r_ *= QSCALE;
                    u16* dst = (which == 0) ? qo : ko;
                    dst[(((size_t)(b * NHEAD + h)) * L_SEQ + l) * 64 + d] = f2bf(r_);
                }
    }
}

// ---------------- generic BK=64 GEMM, residual epilogue ----------------------------
// MODE 0: X fp32, out bf16  (O-proj -> ybuf bf16)
// MODE 1: X bf16, out fp32  (final -> d_out fp32)
template<int MODE>
__global__ __launch_bounds__(256) void gemm_res64(
    const u16* __restrict__ A, const u16* __restrict__ Bt,
    void* __restrict__ outp, const void* __restrict__ X, const float* __restrict__ coef,
    int M, int N, int K)
{
    __shared__ __align__(16) u16 As[2][64 * 64];
    __shared__ __align__(16) u16 Bs[2][128 * 64];
    const int tid = threadIdx.x;
    const int lane = tid & 63, wid = tid >> 6;
    const int lo = lane & 15, hi = lane >> 4;
    const int bm = blockIdx.x * 64, bn = blockIdx.y * 128;
    const int wrow = (wid >> 1) * 32, wcol = (wid & 1) * 64;

    f32x4 acc[2][4];
#pragma unroll
    for (int a = 0; a < 2; a++)
#pragma unroll
        for (int b = 0; b < 4; b++)
            acc[a][b] = (f32x4){0.f, 0.f, 0.f, 0.f};

    auto stage = [&](int buf, int k0) {
#pragma unroll
        for (int p = 0; p < 2; p++) {
            int ch = tid + p * 256;
            int r = ch >> 3, g = ch & 7;
            gload16(A + (size_t)(bm + r) * K + k0 + ((g ^ (r & 7)) * 8), &As[buf][ch * 8]);
        }
#pragma unroll
        for (int p = 0; p < 4; p++) {
            int ch = tid + p * 256;
            int r = ch >> 3, g = ch & 7;
            gload16(Bt + (size_t)(bn + r) * K + k0 + ((g ^ (r & 7)) * 8), &Bs[buf][ch * 8]);
        }
    };

    stage(0, 0);
    int cur = 0;
    const int NT = K >> 6;
    for (int t = 0; t < NT; t++) {
        __syncthreads();
        if (t + 1 < NT) stage(cur ^ 1, (t + 1) * 64);
        short8 af[2][2], bfr[4][2];
#pragma unroll
        for (int mi = 0; mi < 2; mi++) {
            int r = wrow + mi * 16 + lo;
#pragma unroll
            for (int h = 0; h < 2; h++)
                af[mi][h] = *(const short8*)(&As[cur][r * 64 + (((h * 4 + hi) ^ (r & 7)) * 8)]);
        }
#pragma unroll
        for (int nj = 0; nj < 4; nj++) {
            int r = wcol + nj * 16 + lo;
#pragma unroll
            for (int h = 0; h < 2; h++)
                bfr[nj][h] = *(const short8*)(&Bs[cur][r * 64 + (((h * 4 + hi) ^ (r & 7)) * 8)]);
        }
#pragma unroll
        for (int mi = 0; mi < 2; mi++)
#pragma unroll
            for (int nj = 0; nj < 4; nj++) {
                acc[mi][nj] = __builtin_amdgcn_mfma_f32_16x16x32_bf16(af[mi][0], bfr[nj][0], acc[mi][nj], 0, 0, 0);
                acc[mi][nj] = __builtin_amdgcn_mfma_f32_16x16x32_bf16(af[mi][1], bfr[nj][1], acc[mi][nj], 0, 0, 0);
            }
        cur ^= 1;
    }
#pragma unroll
    for (int mi = 0; mi < 2; mi++)
#pragma unroll
        for (int nj = 0; nj < 4; nj++)
#pragma unroll
            for (int i = 0; i < 4; i++) {
                int row = bm + wrow + mi * 16 + hi * 4 + i;
                int col = bn + wcol + nj * 16 + lo;
                size_t idx = (size_t)row * N + col;
                int b = row >> 11;
                float base = (MODE == 0) ? ((const float*)X)[idx]
                                         : bf2f(((const u16*)X)[idx]);
                float v = base + acc[mi][nj][i] * coef[(size_t)b * N + col];
                if (MODE == 0) ((u16*)outp)[idx] = f2bf(v);
                else           ((float*)outp)[idx] = v;
            }
}

// ---------------- fused FFN1, BK=64: ff = bf16(silu(A@G^T) * (A@H^T)) --------------
__global__ __launch_bounds__(256) void gemm_ffn1(
    const u16* __restrict__ A, const u16* __restrict__ Gt, const u16* __restrict__ Ht,
    u16* __restrict__ ff, int M, int N, int K)
{
    __shared__ __align__(16) u16 As[2][128 * 64];
    __shared__ __align__(16) u16 Gs[2][64 * 64];
    __shared__ __align__(16) u16 Hs[2][64 * 64];
    const int tid = threadIdx.x;
    const int lane = tid & 63, wid = tid >> 6;
    const int lo = lane & 15, hi = lane >> 4;
    const int bm = blockIdx.x * 128, bn = blockIdx.y * 64;
    const int wrow = (wid >> 1) * 64, wcol = (wid & 1) * 32;

    f32x4 ag[4][2], ah[4][2];
#pragma unroll
    for (int a = 0; a < 4; a++)
#pragma unroll
        for (int b = 0; b < 2; b++) {
            ag[a][b] = (f32x4){0.f, 0.f, 0.f, 0.f};
            ah[a][b] = (f32x4){0.f, 0.f, 0.f, 0.f};
        }

    auto stage = [&](int buf, int k0) {
#pragma unroll
        for (int p = 0; p < 4; p++) {
            int ch = tid + p * 256;
            int r = ch >> 3, g = ch & 7;
            gload16(A + (size_t)(bm + r) * K + k0 + ((g ^ (r & 7)) * 8), &As[buf][ch * 8]);
        }
#pragma unroll
        for (int p = 0; p < 2; p++) {
            int ch = tid + p * 256;
            int r = ch >> 3, g = ch & 7;
            gload16(Gt + (size_t)(bn + r) * K + k0 + ((g ^ (r & 7)) * 8), &Gs[buf][ch * 8]);
        }
#pragma unroll
        for (int p = 0; p < 2; p++) {
            int ch = tid + p * 256;
            int r = ch >> 3, g = ch & 7;
            gload16(Ht + (size_t)(bn + r) * K + k0 + ((g ^ (r & 7)) * 8), &Hs[buf][ch * 8]);
        }
    };

    stage(0, 0);
    int cur = 0;
    const int NT = K >> 6;
    for (int t = 0; t < NT; t++) {
        __syncthreads();
        if (t + 1 < NT) stage(cur ^ 1, (t + 1) * 64);
        short8 af[4][2], gf[2][2], hf[2][2];
#pragma unroll
        for (int mi = 0; mi < 4; mi++) {
            int r = wrow + mi * 16 + lo;
#pragma unroll
            for (int h = 0; h < 2; h++)
                af[mi][h] = *(const short8*)(&As[cur][r * 64 + (((h * 4 + hi) ^ (r & 7)) * 8)]);
        }
#pragma unroll
        for (int nj = 0; nj < 2; nj++) {
            int r = wcol + nj * 16 + lo;
#pragma unroll
            for (int h = 0; h < 2; h++) {
                gf[nj][h] = *(const short8*)(&Gs[cur][r * 64 + (((h * 4 + hi) ^ (r & 7)) * 8)]);
                hf[nj][h] = *(const short8*)(&Hs[cur][r * 64 + (((h * 4 + hi) ^ (r & 7)) * 8)]);
            }
        }
#pragma unroll
        for (int mi = 0; mi < 4; mi++)
#pragma unroll
            for (int nj = 0; nj < 2; nj++) {
                ag[mi][nj] = __builtin_amdgcn_mfma_f32_16x16x32_bf16(af[mi][0], gf[nj][0], ag[mi][nj], 0, 0, 0);
                ag[mi][nj] = __builtin_amdgcn_mfma_f32_16x16x32_bf16(af[mi][1], gf[nj][1], ag[mi][nj], 0, 0, 0);
                ah[mi][nj] = __builtin_amdgcn_mfma_f32_16x16x32_bf16(af[mi][0], hf[nj][0], ah[mi][nj], 0, 0, 0);
                ah[mi][nj] = __builtin_amdgcn_mfma_f32_16x16x32_bf16(af[mi][1], hf[nj][1], ah[mi][nj], 0, 0, 0);
            }
        cur ^= 1;
    }
#pragma unroll
    for (int mi = 0; mi < 4; mi++)
#pragma unroll
        for (int nj = 0; nj < 2; nj++)
#pragma unroll
            for (int i = 0; i < 4; i++) {
                int row = bm + wrow + mi * 16 + hi * 4 + i;
                int col = bn + wcol + nj * 16 + lo;
                ff[(size_t)row * N + col] = f2bf(silu_f(ag[mi][nj][i]) * ah[mi][nj][i]);
            }
}

// ---------------- flash attention: 512 threads (8 waves), QBLK=128, KVB=128 --------
__global__ __launch_bounds__(512) void attn_fwd(
    const u16* __restrict__ q, const u16* __restrict__ k, const u16* __restrict__ vt,
    u16* __restrict__ outp)
{
    __shared__ __align__(16) u16 Kb[KVB * 64];      // 16 KB
    __shared__ __align__(16) u16 Vb[64 * KVB];      // 16 KB
    __shared__ __align__(16) u16 Ps[8][16 * KVB];   // 32 KB
    const int tid = threadIdx.x;
    const int lane = tid & 63, wid = tid >> 6;      // 8 waves
    const int lo = lane & 15, hi = lane >> 4;
    const int lid = blockIdx.x;
    const int xcd = lid & 7, li = lid >> 3;          // li 0..47
    const int bh = xcd * 3 + (li >> 4);              // 3 heads per XCD
    const int qt = li & 15;                          // 16 q-tiles of 128
    const int b = bh / NHEAD, h = bh % NHEAD;
    const int q0 = qt * QBLK + wid * 16;
    const u16* qb = q + ((size_t)bh * L_SEQ + q0) * 64;
    const u16* kbase = k + (size_t)bh * L_SEQ * 64;
    const u16* vbase = vt + (size_t)bh * 64 * L_SEQ;

    short8 qa0 = *(const short8*)(qb + lo * 64 + hi * 8);
    short8 qa1 = *(const short8*)(qb + lo * 64 + 32 + hi * 8);

    f32x4 oacc[4];
#pragma unroll
    for (int dt = 0; dt < 4; dt++) oacc[dt] = (f32x4){0.f, 0.f, 0.f, 0.f};
    float m_ = -1e30f, ls = 0.f;

    const int rk = tid >> 3, gk = tid & 7;
    const u16* ka = kbase + (size_t)rk * 64 + ((gk ^ (rk & 7)) * 8);
    const int rv = tid >> 4, gv = tid & 15;
    const u16* va = vbase + (size_t)rv * L_SEQ + ((gv ^ (rv & 15)) * 8);
    u16* kdst = &Kb[tid * 8];
    u16* vdst = &Vb[tid * 8];

    int4 kr0, kr1, vr0, vr1;
    kr0 = *(const int4*)(ka);
    kr1 = *(const int4*)(ka + 4096);
    vr0 = *(const int4*)(va);
    vr1 = *(const int4*)(va + 65536);

    const int NT = L_SEQ / KVB;   // 16
    u16* pw = &Ps[wid][0];
    const int pkey = lo << 3;
    for (int t = 0; t < NT; t++) {
        __syncthreads();
        *(int4*)(kdst)        = kr0;
        *(int4*)(kdst + 4096) = kr1;
        *(int4*)(vdst)        = vr0;
        *(int4*)(vdst + 4096) = vr1;
        __syncthreads();
        if (t + 1 < NT) {
            int kv0 = (t + 1) * KVB;
            const u16* kan = ka + (size_t)kv0 * 64;
            const u16* van = va + kv0;
            kr0 = *(const int4*)(kan);
            kr1 = *(const int4*)(kan + 4096);
            vr0 = *(const int4*)(van);
            vr1 = *(const int4*)(van + 65536);
        }
        f32x4 s[8];
#pragma unroll
        for (int nt = 0; nt < 8; nt++) {
            int kr_ = nt * 16 + lo;
            const u16* kp = &Kb[kr_ * 64];
            int key = (kr_ & 7) << 3;
            short8 kf0 = *(const short8*)(kp + ((hi * 8) ^ key));
            short8 kf1 = *(const short8*)(kp + ((32 + hi * 8) ^ key));
            f32x4 z = (f32x4){0.f, 0.f, 0.f, 0.f};
            z = __builtin_amdgcn_mfma_f32_16x16x32_bf16(kf0, qa0, z, 0, 0, 0);
            s[nt] = __builtin_amdgcn_mfma_f32_16x16x32_bf16(kf1, qa1, s[nt] = z, 0, 0, 0);
        }
        float t0 = fmaxf(fmaxf(s[0][0], s[0][1]), fmaxf(s[0][2], s[0][3]));
        float t1 = fmaxf(fmaxf(s[1][0], s[1][1]), fmaxf(s[1][2], s[1][3]));
        float t2 = fmaxf(fmaxf(s[2][0], s[2][1]), fmaxf(s[2][2], s[2][3]));
        float t3 = fmaxf(fmaxf(s[3][0], s[3][1]), fmaxf(s[3][2], s[3][3]));
        float t4 = fmaxf(fmaxf(s[4][0], s[4][1]), fmaxf(s[4][2], s[4][3]));
        float t5 = fmaxf(fmaxf(s[5][0], s[5][1]), fmaxf(s[5][2], s[5][3]));
        float t6 = fmaxf(fmaxf(s[6][0], s[6][1]), fmaxf(s[6][2], s[6][3]));
        float t7 = fmaxf(fmaxf(s[7][0], s[7][1]), fmaxf(s[7][2], s[7][3]));
        float pmax = fmaxf(fmaxf(fmaxf(t0, t1), fmaxf(t2, t3)),
                           fmaxf(fmaxf(t4, t5), fmaxf(t6, t7)));
        pmax = fmaxf(pmax, __shfl_xor(pmax, 16));
        pmax = fmaxf(pmax, __shfl_xor(pmax, 32));
        if (!__all(pmax - m_ <= 8.f)) {
            float mn = fmaxf(m_, pmax);
            float al = exp2f(m_ - mn);
            m_ = mn;
            ls *= al;
#pragma unroll
            for (int dt = 0; dt < 4; dt++) oacc[dt] *= al;
        }
        float rsA = 0.f, rsB = 0.f, rsC = 0.f, rsD = 0.f;
#pragma unroll
        for (int nt = 0; nt < 8; nt++) {
            float p0 = exp2f(s[nt][0] - m_);
            float p1 = exp2f(s[nt][1] - m_);
            float p2 = exp2f(s[nt][2] - m_);
            float p3 = exp2f(s[nt][3] - m_);
            s[nt][0] = p0; s[nt][1] = p1; s[nt][2] = p2; s[nt][3] = p3;
            rsA += p0; rsB += p1; rsC += p2; rsD += p3;
        }
        ls += (rsA + rsB) + (rsC + rsD);
#pragma unroll
        for (int nt = 0; nt < 8; nt++) {
            unsigned w0, w1;
            asm("v_cvt_pk_bf16_f32 %0, %1, %2" : "=v"(w0) : "v"(s[nt][0]), "v"(s[nt][1]));
            asm("v_cvt_pk_bf16_f32 %0, %1, %2" : "=v"(w1) : "v"(s[nt][2]), "v"(s[nt][3]));
            uint2 pk2; pk2.x = w0; pk2.y = w1;
            *(uint2*)(pw + lo * KVB + ((nt * 16 + hi * 4) ^ pkey)) = pk2;
        }
        short8 pa0 = *(const short8*)(pw + lo * KVB + ((0 * 32 + hi * 8) ^ pkey));
        short8 pa1 = *(const short8*)(pw + lo * KVB + ((1 * 32 + hi * 8) ^ pkey));
        short8 pa2 = *(const short8*)(pw + lo * KVB + ((2 * 32 + hi * 8) ^ pkey));
        short8 pa3 = *(const short8*)(pw + lo * KVB + ((3 * 32 + hi * 8) ^ pkey));
#pragma unroll
        for (int dt = 0; dt < 4; dt++) {
            int vr_ = dt * 16 + lo;
            const u16* vp = &Vb[vr_ * KVB];
            int vkey = (vr_ & 15) << 3;
            short8 vf0 = *(const short8*)(vp + ((0 * 32 + hi * 8) ^ vkey));
            short8 vf1 = *(const short8*)(vp + ((1 * 32 + hi * 8) ^ vkey));
            short8 vf2 = *(const short8*)(vp + ((2 * 32 + hi * 8) ^ vkey));
            short8 vf3 = *(const short8*)(vp + ((3 * 32 + hi * 8) ^ vkey));
            oacc[dt] = __builtin_amdgcn_mfma_f32_16x16x32_bf16(vf0, pa0, oacc[dt], 0, 0, 0);
            oacc[dt] = __builtin_amdgcn_mfma_f32_16x16x32_bf16(vf1, pa1, oacc[dt], 0, 0, 0);
            oacc[dt] = __builtin_amdgcn_mfma_f32_16x16x32_bf16(vf2, pa2, oacc[dt], 0, 0, 0);
            oacc[dt] = __builtin_amdgcn_mfma_f32_16x16x32_bf16(vf3, pa3, oacc[dt], 0, 0, 0);
        }
    }
    ls += __shfl_xor(ls, 16);
    ls += __shfl_xor(ls, 32);
    float inv = 1.f / ls;
    int qrow = q0 + lo;
    u16* orow = outp + ((size_t)(b * L_SEQ + qrow)) * 768 + h * 64;
#pragma unroll
    for (int dt = 0; dt < 4; dt++) {
        unsigned w0, w1;
        float o0 = oacc[dt][0] * inv, o1 = oacc[dt][1] * inv;
        float o2 = oacc[dt][2] * inv, o3 = oacc[dt][3] * inv;
        asm("v_cvt_pk_bf16_f32 %0, %1, %2" : "=v"(w0) : "v"(o0), "v"(o1));
        asm("v_cvt_pk_bf16_f32 %0, %1, %2" : "=v"(w1) : "v"(o2), "v"(o3));
        uint2 pk2; pk2.x = w0; pk2.y = w1;
        *(uint2*)(orow + dt * 16 + hi * 4) = pk2;
    }
}

extern "C" void kernel_launch(void* const* d_in, const int* in_sizes, int n_in,
                              void* d_out, int out_size, void* d_ws, size_t ws_size,
                              hipStream_t stream)
{
    const float* x      = (const float*)d_in[0];
    const float* c      = (const float*)d_in[1];
    const float* fcos   = (const float*)d_in[2];
    const float* fsin   = (const float*)d_in[3];
    const float* Wq     = (const float*)d_in[4];
    const float* Wk     = (const float*)d_in[5];
    const float* Wv     = (const float*)d_in[6];
    const float* Wo     = (const float*)d_in[7];
    const float* cw1    = (const float*)d_in[8];
    const float* cb1    = (const float*)d_in[9];
    const float* cw2    = (const float*)d_in[10];
    const float* cb2    = (const float*)d_in[11];
    const float* anw    = (const float*)d_in[12];
    const float* Walpha = (const float*)d_in[13];
    const float* Wbeta  = (const float*)d_in[14];
    const float* Wgamma = (const float*)d_in[15];
    const float* Wgate  = (const float*)d_in[16];
    const float* Whid   = (const float*)d_in[17];
    const float* Wout   = (const float*)d_in[18];
    const float* fnw    = (const float*)d_in[19];
    const float* Wbetaf = (const float*)d_in[20];
    const float* Wgammaf= (const float*)d_in[21];

    const int M = 4096; // B*L
    char* ws = (char*)d_ws;
    size_t off = 0;
    auto alloc = [&](size_t bytes) -> char* {
        char* p = ws + off;
        off += (bytes + 255) & ~(size_t)255;
        return p;
    };
    u16* wq_t   = (u16*)alloc((size_t)768 * 768 * 2);
    u16* wk_t   = (u16*)alloc((size_t)768 * 768 * 2);
    u16* wv_t   = (u16*)alloc((size_t)768 * 768 * 2);
    u16* wo_t   = (u16*)alloc((size_t)768 * 768 * 2);
    u16* gate_t = (u16*)alloc((size_t)3072 * 768 * 2);
    u16* hid_t  = (u16*)alloc((size_t)3072 * 768 * 2);
    u16* out_t  = (u16*)alloc((size_t)768 * 3072 * 2);
    float* part1 = (float*)alloc((size_t)8 * 2 * 3072 * 4);
    float* part2 = (float*)alloc((size_t)8 * 2 * 768 * 4);
    float* mods = (float*)alloc(5 * 2 * 768 * 4);
    u16* hbuf   = (u16*)alloc((size_t)M * 768 * 2);
    u16* qrope  = (u16*)alloc((size_t)M * 768 * 2);
    u16* krope  = (u16*)alloc((size_t)M * 768 * 2);
    u16* vtb    = (u16*)alloc((size_t)M * 768 * 2);
    u16* attnh  = (u16*)alloc((size_t)M * 768 * 2);
    u16* ybuf   = (u16*)alloc((size_t)M * 768 * 2);
    u16* ffbuf  = (u16*)alloc((size_t)M * 3072 * 2);

    // 1. ALL weight transposes in one launch
    transpose_all<<<9216, 256, 0, stream>>>(
        Wq, Wk, Wv, Wo, Wgate, Whid, Wout,
        wq_t, wk_t, wv_t, wo_t, gate_t, hid_t, out_t);

    // 2. conditioning path
    cond_mlp1<<<dim3(12, 8), 256, 0, stream>>>(c, cw1, part1);
    cond_mlp2<<<dim3(12, 8), 256, 0, stream>>>(part1, cb1, cw2, part2);
    mod_gemm<<<dim3(12, 5), 256, 0, stream>>>(
        part2, cb2, Wgamma, Wbeta, Walpha, Wgammaf, Wbetaf, mods);

    // 3. h = rms(x)*gamma_a + beta_a (fp32 input; wave-per-row, grid 1024)
    rmsnorm_mod<0><<<1024, 256, 0, stream>>>(x, anw, mods + 0 * 1536, mods + 1 * 1536, hbuf);

    // 4. fused QKV GEMM + RoPE + V-transpose epilogue
    gemm_qkv_rope<<<dim3(32, 18), 256, 0, stream>>>(
        hbuf, wq_t, fcos, fsin, qrope, krope, vtb, M, 2304, 768);

    // 5. attention -> attnh (B,L,D) bf16
    attn_fwd<<<dim3(384), 512, 0, stream>>>(qrope, krope, vtb, attnh);

    // 6. O-proj + residual: ybuf(bf16) = x + (attnh @ Wo) * alpha_a
    gemm_res64<0><<<dim3(64, 6), 256, 0, stream>>>(
        attnh, wo_t, ybuf, x, mods + 2 * 1536, M, 768, 768);

    // 7. h2 = rms(y)*gamma_f + beta_f (bf16 input; wave-per-row, grid 1024)
    rmsnorm_mod<1><<<1024, 256, 0, stream>>>(ybuf, fnw, mods + 3 * 1536, mods + 4 * 1536, hbuf);

    // 8. fused gate/hidden GEMM + silu-mul -> ffbuf
    gemm_ffn1<<<dim3(32, 48), 256, 0, stream>>>(
        hbuf, gate_t, hid_t, ffbuf, M, 3072, 768);

    // 9. out(fp32) = y(bf16) + (ff @ Wout) * gamma_f
    gemm_res64<1><<<dim3(64, 6), 256, 0, stream>>>(
        ffbuf, out_t, d_out, ybuf, mods + 3 * 1536, M, 768, 3072);
}